// Round 1
// baseline (49397.540 us; speedup 1.0000x reference)
//
#include <hip/hip_runtime.h>

// ---------------------------------------------------------------------------
// Sparse 3D conv backbone (VoxelResBackBone8x / VoxelNeXt SPS) — fp32.
// Structure per forward:
//   conv_input (5->16, rb1) + BN + ReLU
//   2x BasicBlock @16 (rb1)
//   pruning: imp=sigmoid(conv 16->1), x*=imp, exact top-k(N/2) threshold mask
//   strided conv 16->32 (rbd) + BN + ReLU
//   2x BasicBlock @32 (rb2)  -> d_out (n2 x 32)
// Notes:
//  - bias-before-BN cancels exactly (BN(x+c)==BN(x)); bb1/bb2 ignored.
//  - rulebook valid entries are a prefix; counts found by binary search.
// ---------------------------------------------------------------------------

__global__ void rb_count_kernel(const int* __restrict__ rout, int P, int n_out,
                                int* __restrict__ cnt) {
    int k = threadIdx.x;
    if (k >= 27) return;
    const int* r = rout + (size_t)k * P;
    int lo = 0, hi = P;              // first index with r[i] >= n_out (sentinel)
    while (lo < hi) {
        int mid = (lo + hi) >> 1;
        if (r[mid] < n_out) lo = mid + 1; else hi = mid;
    }
    cnt[k] = lo;
}

template <int CIN, int COUT>
__global__ __launch_bounds__(256) void conv_scatter(
        const float* __restrict__ feat, const float* __restrict__ W,
        const int* __restrict__ rin, const int* __restrict__ rout,
        const int* __restrict__ cnt, int P, float* __restrict__ out) {
    const int k = blockIdx.y;
    const int c = cnt[k];
    const int p0 = blockIdx.x * 256;
    if (p0 >= c) return;                       // uniform early exit (padding)
    __shared__ float Ws[CIN * COUT];
    for (int i = threadIdx.x; i < CIN * COUT; i += 256)
        Ws[i] = W[k * CIN * COUT + i];
    __syncthreads();
    const int p = p0 + threadIdx.x;
    if (p >= c) return;
    const int gi = rin[(size_t)k * P + p];
    const int go = rout[(size_t)k * P + p];
    float f[CIN];
#pragma unroll
    for (int ci = 0; ci < CIN; ci++) f[ci] = feat[(size_t)gi * CIN + ci];
    float acc[COUT];
#pragma unroll
    for (int co = 0; co < COUT; co++) acc[co] = 0.f;
#pragma unroll
    for (int ci = 0; ci < CIN; ci++) {
        const float fv = f[ci];
#pragma unroll
        for (int co = 0; co < COUT; co++) acc[co] += fv * Ws[ci * COUT + co];
    }
#pragma unroll
    for (int co = 0; co < COUT; co++)
        atomicAdd(&out[(size_t)go * COUT + co], acc[co]);
}

template <int C>
__global__ __launch_bounds__(256) void bn_stats(const float* __restrict__ x, int n,
                                                float* __restrict__ stats) {
    const int G = 256 / C;
    const int t = threadIdx.x;
    const int ch = t & (C - 1);
    const int g = t / C;
    float s = 0.f, s2 = 0.f;
    for (long long r = (long long)blockIdx.x * G + g; r < n;
         r += (long long)gridDim.x * G) {
        float v = x[r * C + ch];
        s += v; s2 += v * v;
    }
    __shared__ float ls[256], ls2[256];
    ls[t] = s; ls2[t] = s2;
    __syncthreads();
#pragma unroll
    for (int st = 128; st >= C; st >>= 1) {
        if (t < st) { ls[t] += ls[t + st]; ls2[t] += ls2[t + st]; }
        __syncthreads();
    }
    if (t < C) { atomicAdd(&stats[t], ls[t]); atomicAdd(&stats[C + t], ls2[t]); }
}

template <int C, bool RELU>
__global__ void bn_apply(const float* __restrict__ x, const float* __restrict__ stats,
                         const float* __restrict__ gg, const float* __restrict__ bb,
                         int n, float* __restrict__ y) {
    const float nf = (float)n;
    const long long total = (long long)n * C;
    for (long long idx = (long long)blockIdx.x * blockDim.x + threadIdx.x;
         idx < total; idx += (long long)gridDim.x * blockDim.x) {
        int ch = (int)(idx & (C - 1));
        float m = stats[ch] / nf;
        float v = stats[C + ch] / nf - m * m;
        float r = rsqrtf(v + 1e-3f);
        float val = gg[ch] * (x[idx] - m) * r + bb[ch];
        if (RELU) val = fmaxf(val, 0.f);
        y[idx] = val;
    }
}

template <int C>
__global__ void bn_apply_addrelu(const float* __restrict__ x,
                                 const float* __restrict__ skip,
                                 const float* __restrict__ stats,
                                 const float* __restrict__ gg,
                                 const float* __restrict__ bb,
                                 int n, float* __restrict__ y) {
    const float nf = (float)n;
    const long long total = (long long)n * C;
    for (long long idx = (long long)blockIdx.x * blockDim.x + threadIdx.x;
         idx < total; idx += (long long)gridDim.x * blockDim.x) {
        int ch = (int)(idx & (C - 1));
        float m = stats[ch] / nf;
        float v = stats[C + ch] / nf - m * m;
        float r = rsqrtf(v + 1e-3f);
        float val = gg[ch] * (x[idx] - m) * r + bb[ch] + skip[idx];
        y[idx] = fmaxf(val, 0.f);
    }
}

__global__ void sigmoid_k(float* __restrict__ x, int n) {
    int i = blockIdx.x * blockDim.x + threadIdx.x;
    if (i < n) x[i] = 1.f / (1.f + expf(-x[i]));
}

__global__ void hist_hi(const float* __restrict__ imp, int n, int* __restrict__ hist) {
    for (int i = blockIdx.x * blockDim.x + threadIdx.x; i < n;
         i += gridDim.x * blockDim.x) {
        unsigned b = __float_as_uint(imp[i]) >> 16;
        atomicAdd(&hist[b], 1);
    }
}

__global__ void hist_lo(const float* __restrict__ imp, int n,
                        const int* __restrict__ state, int* __restrict__ hist) {
    unsigned hb = (unsigned)state[0];
    for (int i = blockIdx.x * blockDim.x + threadIdx.x; i < n;
         i += gridDim.x * blockDim.x) {
        unsigned b = __float_as_uint(imp[i]);
        if ((b >> 16) == hb) atomicAdd(&hist[b & 0xffffu], 1);
    }
}

// phase 0: find high-16 bucket of kkeep-th largest -> state[0], remaining -> state[1]
// phase 1: refine low-16 within bucket -> exact kth bits -> state[2]
__global__ __launch_bounds__(256) void scan_sel(const int* __restrict__ hist,
                                                int kkeep, int phase,
                                                int* __restrict__ state) {
    __shared__ int csum[256];
    __shared__ int bins[256];
    __shared__ int sel_c, rem_c;
    const int t = threadIdx.x;
    const int target = (phase == 0) ? kkeep : state[1];
    int s = 0;
    const int* h = hist + t * 256;
    for (int i = 0; i < 256; i++) s += h[i];
    csum[t] = s;
    __syncthreads();
    if (t == 0) {
        int acc = 0; int c = 255;
        for (; c > 0; c--) {
            if (acc + csum[c] >= target) break;
            acc += csum[c];
        }
        sel_c = c; rem_c = target - acc;
    }
    __syncthreads();
    bins[t] = hist[sel_c * 256 + t];
    __syncthreads();
    if (t == 0) {
        int rem = rem_c;
        int acc = 0; int b = 255;
        for (; b > 0; b--) {
            if (acc + bins[b] >= rem) break;
            acc += bins[b];
        }
        int bucket = sel_c * 256 + b;
        if (phase == 0) { state[0] = bucket; state[1] = rem - acc; }
        else            { state[2] = (int)(((unsigned)state[0] << 16) | (unsigned)bucket); }
    }
}

__global__ void prune_mask(float* __restrict__ x, const float* __restrict__ imp,
                           const int* __restrict__ state, int n) {
    const unsigned K = (unsigned)state[2];
    int i = blockIdx.x * blockDim.x + threadIdx.x;
    if (i >= n) return;
    float im = imp[i];
    float mult = (__float_as_uint(im) >= K) ? im : 0.f;
#pragma unroll
    for (int c = 0; c < 16; c++) x[(size_t)i * 16 + c] *= mult;
}

extern "C" void kernel_launch(void* const* d_in, const int* in_sizes, int n_in,
                              void* d_out, int out_size, void* d_ws, size_t ws_size,
                              hipStream_t stream) {
    const float* vf    = (const float*)d_in[0];
    const float* W_in  = (const float*)d_in[1];
    const float* g_in  = (const float*)d_in[2];
    const float* b_in  = (const float*)d_in[3];
    const float* Wb1   = (const float*)d_in[4];
    // d_in[5] = bb1 (cancels in BN)
    const float* gb1   = (const float*)d_in[6];
    const float* beb1  = (const float*)d_in[7];
    const float* Wp    = (const float*)d_in[8];
    const float* Wd    = (const float*)d_in[9];
    const float* g_d   = (const float*)d_in[10];
    const float* b_d   = (const float*)d_in[11];
    const float* Wb2   = (const float*)d_in[12];
    // d_in[13] = bb2 (cancels in BN)
    const float* gb2   = (const float*)d_in[14];
    const float* beb2  = (const float*)d_in[15];
    const int* rb1_in  = (const int*)d_in[16];
    const int* rb1_out = (const int*)d_in[17];
    const int* rbd_in  = (const int*)d_in[18];
    const int* rbd_out = (const int*)d_in[19];
    const int* rb2_in  = (const int*)d_in[20];
    const int* rb2_out = (const int*)d_in[21];
    // d_in[22] = n2 scalar (device); use out_size instead.

    const int N  = in_sizes[0] / 5;
    const int P1 = in_sizes[16] / 27;
    const int Pd = in_sizes[18] / 27;
    const int P2 = in_sizes[20] / 27;
    const int n2 = out_size / 32;
    const int kkeep = N - N / 2;

    float* base  = (float*)d_ws;
    float* A     = base;                       // 16ch x  (N)
    float* B     = A  + (size_t)N * 16;        // 16ch
    float* Cb    = B  + (size_t)N * 16;        // 16ch
    float* D     = Cb + (size_t)N * 16;        // 32ch x (n2)
    float* E     = D  + (size_t)n2 * 32;       // 32ch
    float* imp   = E  + (size_t)n2 * 32;       // N
    float* stats = imp + (size_t)N;            // 64
    int*   cnt1  = (int*)(stats + 64);
    int*   cntd  = cnt1 + 32;
    int*   cnt2  = cntd + 32;
    int*   hist  = cnt2 + 32;                  // 65536
    int*   state = hist + 65536;               // 8
    float* OUT   = (float*)d_out;

    const int g1  = (P1 + 255) / 256;
    const int gd  = (Pd + 255) / 256;
    const int g2  = (P2 + 255) / 256;
    const int gew = 2048;

    // rulebook valid counts (valid entries are a prefix)
    rb_count_kernel<<<1, 32, 0, stream>>>(rb1_out, P1, N,  cnt1);
    rb_count_kernel<<<1, 32, 0, stream>>>(rbd_out, Pd, n2, cntd);
    rb_count_kernel<<<1, 32, 0, stream>>>(rb2_out, P2, n2, cnt2);

    // ---- conv_input: (N,5)->(N,16), BN, ReLU -> A
    hipMemsetAsync(B, 0, (size_t)N * 16 * 4, stream);
    conv_scatter<5, 16><<<dim3(g1, 27), 256, 0, stream>>>(vf, W_in, rb1_in, rb1_out, cnt1, P1, B);
    hipMemsetAsync(stats, 0, 64 * 4, stream);
    bn_stats<16><<<512, 256, 0, stream>>>(B, N, stats);
    bn_apply<16, true><<<gew, 256, 0, stream>>>(B, stats, g_in, b_in, N, A);

    // ---- conv1: 2x SparseBasicBlock @16
    for (int i = 0; i < 2; i++) {
        const float* W0 = Wb1 + (size_t)(i * 2 + 0) * 27 * 256;
        const float* W1 = Wb1 + (size_t)(i * 2 + 1) * 27 * 256;
        hipMemsetAsync(B, 0, (size_t)N * 16 * 4, stream);
        conv_scatter<16, 16><<<dim3(g1, 27), 256, 0, stream>>>(A, W0, rb1_in, rb1_out, cnt1, P1, B);
        hipMemsetAsync(stats, 0, 64 * 4, stream);
        bn_stats<16><<<512, 256, 0, stream>>>(B, N, stats);
        bn_apply<16, true><<<gew, 256, 0, stream>>>(B, stats, gb1 + (i * 2 + 0) * 16, beb1 + (i * 2 + 0) * 16, N, B);
        hipMemsetAsync(Cb, 0, (size_t)N * 16 * 4, stream);
        conv_scatter<16, 16><<<dim3(g1, 27), 256, 0, stream>>>(B, W1, rb1_in, rb1_out, cnt1, P1, Cb);
        hipMemsetAsync(stats, 0, 64 * 4, stream);
        bn_stats<16><<<512, 256, 0, stream>>>(Cb, N, stats);
        bn_apply_addrelu<16><<<gew, 256, 0, stream>>>(Cb, A, stats, gb1 + (i * 2 + 1) * 16, beb1 + (i * 2 + 1) * 16, N, A);
    }

    // ---- pruning: imp = sigmoid(conv 16->1); exact top-k threshold; mask
    hipMemsetAsync(imp, 0, (size_t)N * 4, stream);
    conv_scatter<16, 1><<<dim3(g1, 27), 256, 0, stream>>>(A, Wp, rb1_in, rb1_out, cnt1, P1, imp);
    sigmoid_k<<<(N + 255) / 256, 256, 0, stream>>>(imp, N);
    hipMemsetAsync(hist, 0, 65536 * 4, stream);
    hist_hi<<<512, 256, 0, stream>>>(imp, N, hist);
    scan_sel<<<1, 256, 0, stream>>>(hist, kkeep, 0, state);
    hipMemsetAsync(hist, 0, 65536 * 4, stream);
    hist_lo<<<512, 256, 0, stream>>>(imp, N, state, hist);
    scan_sel<<<1, 256, 0, stream>>>(hist, kkeep, 1, state);
    prune_mask<<<(N + 255) / 256, 256, 0, stream>>>(A, imp, state, N);

    // ---- strided downsample 16->32 + BN + ReLU -> D
    hipMemsetAsync(D, 0, (size_t)n2 * 32 * 4, stream);
    conv_scatter<16, 32><<<dim3(gd, 27), 256, 0, stream>>>(A, Wd, rbd_in, rbd_out, cntd, Pd, D);
    hipMemsetAsync(stats, 0, 64 * 4, stream);
    bn_stats<32><<<512, 256, 0, stream>>>(D, n2, stats);
    bn_apply<32, true><<<gew, 256, 0, stream>>>(D, stats, g_d, b_d, n2, D);

    // ---- conv2: 2x SparseBasicBlock @32 (d_out doubles as conv scratch)
    for (int i = 0; i < 2; i++) {
        const float* W0 = Wb2 + (size_t)(i * 2 + 0) * 27 * 1024;
        const float* W1 = Wb2 + (size_t)(i * 2 + 1) * 27 * 1024;
        hipMemsetAsync(E, 0, (size_t)n2 * 32 * 4, stream);
        conv_scatter<32, 32><<<dim3(g2, 27), 256, 0, stream>>>(D, W0, rb2_in, rb2_out, cnt2, P2, E);
        hipMemsetAsync(stats, 0, 64 * 4, stream);
        bn_stats<32><<<512, 256, 0, stream>>>(E, n2, stats);
        bn_apply<32, true><<<gew, 256, 0, stream>>>(E, stats, gb2 + (i * 2 + 0) * 32, beb2 + (i * 2 + 0) * 32, n2, E);
        hipMemsetAsync(OUT, 0, (size_t)n2 * 32 * 4, stream);
        conv_scatter<32, 32><<<dim3(g2, 27), 256, 0, stream>>>(E, W1, rb2_in, rb2_out, cnt2, P2, OUT);
        hipMemsetAsync(stats, 0, 64 * 4, stream);
        bn_stats<32><<<512, 256, 0, stream>>>(OUT, n2, stats);
        bn_apply_addrelu<32><<<gew, 256, 0, stream>>>(OUT, D, stats, gb2 + (i * 2 + 1) * 32, beb2 + (i * 2 + 1) * 32, n2, (i == 0) ? D : OUT);
    }
}

// Round 2
// 3556.631 us; speedup vs baseline: 13.8889x; 13.8889x over previous
//
#include <hip/hip_runtime.h>

// ---------------------------------------------------------------------------
// Sparse 3D conv backbone — fp32, gather formulation (no conv atomics).
//   conv_input (5->16, rb1) + BN + ReLU
//   2x BasicBlock @16 (rb1)
//   pruning: imp=sigmoid(conv 16->1), x*=imp, exact top-k(N/2) threshold mask
//   strided conv 16->32 (rbd, dense inverse map) + BN + ReLU
//   2x BasicBlock @32 (rb2)  -> d_out (n2 x 32)
// Facts used:
//  - bias-before-BN cancels exactly (BN(x+c)==BN(x)); bb1/bb2 ignored.
//  - rb1/rb2 rout[k] sorted ascending + unique per offset (subm rulebook).
//  - rbd rout[k] unsorted but unique per (k, out) -> dense inverse map.
//  - valid rulebook entries are a prefix; counts by monotone binary search.
// ---------------------------------------------------------------------------

__global__ void rb_count_kernel(const int* __restrict__ rout, int P, int n_out,
                                int* __restrict__ cnt) {
    int k = threadIdx.x;
    if (k >= 27) return;
    const int* r = rout + (size_t)k * P;
    int lo = 0, hi = P;              // first index with r[i] >= n_out (sentinel)
    while (lo < hi) {
        int mid = (lo + hi) >> 1;
        if (r[mid] < n_out) lo = mid + 1; else hi = mid;
    }
    cnt[k] = lo;
}

__global__ void inv_build(const int* __restrict__ rin, const int* __restrict__ rout,
                          const int* __restrict__ cnt, int P, int n_out,
                          int* __restrict__ inv) {
    const int k = blockIdx.y;
    const int p = blockIdx.x * 256 + threadIdx.x;
    if (p < cnt[k])
        inv[(size_t)k * n_out + rout[(size_t)k * P + p]] = rin[(size_t)k * P + p];
}

// Gather conv for sorted-unique rulebooks (rb1, rb2). Block = 256 outputs.
template <int CIN, int COUT>
__global__ __launch_bounds__(256) void conv_gather_sorted(
        const float* __restrict__ feat, const float* __restrict__ W,
        const int* __restrict__ rin, const int* __restrict__ rout,
        const int* __restrict__ cnt, int P, int n_out, float* __restrict__ out) {
    __shared__ float Ws[CIN * COUT];
    __shared__ int invl[27 * 256];
    __shared__ int seg[56];
    const int t = threadIdx.x;
    const int j0 = blockIdx.x * 256;
    const int j = j0 + t;

    for (int i = t; i < 27 * 256; i += 256) invl[i] = -1;
    if (t < 54) {  // hoisted binary searches: k = t>>1, bound = j0 or j0+256
        const int k = t >> 1;
        const int target = j0 + ((t & 1) ? 256 : 0);
        const int* r = rout + (size_t)k * P;
        int lo = 0, hi = cnt[k];
        while (lo < hi) {
            int mid = (lo + hi) >> 1;
            if (r[mid] < target) lo = mid + 1; else hi = mid;
        }
        seg[t] = lo;
    }
    __syncthreads();
    for (int k = 0; k < 27; k++) {   // scatter segments into local inverse map
        const int idx = seg[2 * k] + t;
        if (idx < seg[2 * k + 1]) {
            const int jj = rout[(size_t)k * P + idx];
            invl[k * 256 + (jj - j0)] = rin[(size_t)k * P + idx];
        }
    }

    float acc[COUT];
#pragma unroll
    for (int co = 0; co < COUT; co++) acc[co] = 0.f;

    for (int k = 0; k < 27; k++) {
        __syncthreads();                         // protects invl (k=0) / Ws reuse
        if (seg[2 * k] == seg[2 * k + 1]) continue;   // block-uniform skip
        for (int i = t; i < CIN * COUT; i += 256) Ws[i] = W[k * CIN * COUT + i];
        __syncthreads();
        const int in = invl[k * 256 + t];
        if (in >= 0) {
            float f[CIN];
            if constexpr (CIN % 4 == 0) {
#pragma unroll
                for (int q = 0; q < CIN / 4; q++) {
                    float4 v = *(const float4*)(feat + (size_t)in * CIN + 4 * q);
                    f[4 * q] = v.x; f[4 * q + 1] = v.y;
                    f[4 * q + 2] = v.z; f[4 * q + 3] = v.w;
                }
            } else {
#pragma unroll
                for (int ci = 0; ci < CIN; ci++) f[ci] = feat[(size_t)in * CIN + ci];
            }
#pragma unroll
            for (int ci = 0; ci < CIN; ci++) {
                const float fv = f[ci];
#pragma unroll
                for (int co = 0; co < COUT; co++) acc[co] += fv * Ws[ci * COUT + co];
            }
        }
    }
    if (j < n_out) {
#pragma unroll
        for (int co = 0; co < COUT; co++) out[(size_t)j * COUT + co] = acc[co];
    }
}

// Gather conv via dense inverse map (strided rulebook).
template <int CIN, int COUT>
__global__ __launch_bounds__(256) void conv_gather_inv(
        const float* __restrict__ feat, const float* __restrict__ W,
        const int* __restrict__ inv, int n_out, float* __restrict__ out) {
    __shared__ float Ws[CIN * COUT];
    const int t = threadIdx.x;
    const int j = blockIdx.x * 256 + t;
    float acc[COUT];
#pragma unroll
    for (int co = 0; co < COUT; co++) acc[co] = 0.f;
    for (int k = 0; k < 27; k++) {
        __syncthreads();
        for (int i = t; i < CIN * COUT; i += 256) Ws[i] = W[k * CIN * COUT + i];
        __syncthreads();
        const int in = (j < n_out) ? inv[(size_t)k * n_out + j] : -1;
        if (in >= 0) {
            float f[CIN];
#pragma unroll
            for (int q = 0; q < CIN / 4; q++) {
                float4 v = *(const float4*)(feat + (size_t)in * CIN + 4 * q);
                f[4 * q] = v.x; f[4 * q + 1] = v.y;
                f[4 * q + 2] = v.z; f[4 * q + 3] = v.w;
            }
#pragma unroll
            for (int ci = 0; ci < CIN; ci++) {
                const float fv = f[ci];
#pragma unroll
                for (int co = 0; co < COUT; co++) acc[co] += fv * Ws[ci * COUT + co];
            }
        }
    }
    if (j < n_out) {
#pragma unroll
        for (int co = 0; co < COUT; co++) out[(size_t)j * COUT + co] = acc[co];
    }
}

template <int C>
__global__ __launch_bounds__(256) void bn_stats(const float* __restrict__ x, int n,
                                                float* __restrict__ stats) {
    const int G = 256 / C;
    const int t = threadIdx.x;
    const int ch = t & (C - 1);
    const int g = t / C;
    float s = 0.f, s2 = 0.f;
    for (long long r = (long long)blockIdx.x * G + g; r < n;
         r += (long long)gridDim.x * G) {
        float v = x[r * C + ch];
        s += v; s2 += v * v;
    }
    __shared__ float ls[256], ls2[256];
    ls[t] = s; ls2[t] = s2;
    __syncthreads();
#pragma unroll
    for (int st = 128; st >= C; st >>= 1) {
        if (t < st) { ls[t] += ls[t + st]; ls2[t] += ls2[t + st]; }
        __syncthreads();
    }
    if (t < C) { atomicAdd(&stats[t], ls[t]); atomicAdd(&stats[C + t], ls2[t]); }
}

template <int C, bool RELU>
__global__ void bn_apply(const float* __restrict__ x, const float* __restrict__ stats,
                         const float* __restrict__ gg, const float* __restrict__ bb,
                         int n, float* __restrict__ y) {
    const float nf = (float)n;
    const long long total = (long long)n * C;
    for (long long idx = (long long)blockIdx.x * blockDim.x + threadIdx.x;
         idx < total; idx += (long long)gridDim.x * blockDim.x) {
        int ch = (int)(idx & (C - 1));
        float m = stats[ch] / nf;
        float v = stats[C + ch] / nf - m * m;
        float r = rsqrtf(v + 1e-3f);
        float val = gg[ch] * (x[idx] - m) * r + bb[ch];
        if (RELU) val = fmaxf(val, 0.f);
        y[idx] = val;
    }
}

template <int C>
__global__ void bn_apply_addrelu(const float* __restrict__ x,
                                 const float* __restrict__ skip,
                                 const float* __restrict__ stats,
                                 const float* __restrict__ gg,
                                 const float* __restrict__ bb,
                                 int n, float* __restrict__ y) {
    const float nf = (float)n;
    const long long total = (long long)n * C;
    for (long long idx = (long long)blockIdx.x * blockDim.x + threadIdx.x;
         idx < total; idx += (long long)gridDim.x * blockDim.x) {
        int ch = (int)(idx & (C - 1));
        float m = stats[ch] / nf;
        float v = stats[C + ch] / nf - m * m;
        float r = rsqrtf(v + 1e-3f);
        float val = gg[ch] * (x[idx] - m) * r + bb[ch] + skip[idx];
        y[idx] = fmaxf(val, 0.f);
    }
}

__global__ void sigmoid_k(float* __restrict__ x, int n) {
    int i = blockIdx.x * blockDim.x + threadIdx.x;
    if (i < n) x[i] = 1.f / (1.f + expf(-x[i]));
}

__global__ void hist_hi(const float* __restrict__ imp, int n, int* __restrict__ hist) {
    for (int i = blockIdx.x * blockDim.x + threadIdx.x; i < n;
         i += gridDim.x * blockDim.x) {
        unsigned b = __float_as_uint(imp[i]) >> 16;
        atomicAdd(&hist[b], 1);
    }
}

__global__ void hist_lo(const float* __restrict__ imp, int n,
                        const int* __restrict__ state, int* __restrict__ hist) {
    unsigned hb = (unsigned)state[0];
    for (int i = blockIdx.x * blockDim.x + threadIdx.x; i < n;
         i += gridDim.x * blockDim.x) {
        unsigned b = __float_as_uint(imp[i]);
        if ((b >> 16) == hb) atomicAdd(&hist[b & 0xffffu], 1);
    }
}

__global__ __launch_bounds__(256) void scan_sel(const int* __restrict__ hist,
                                                int kkeep, int phase,
                                                int* __restrict__ state) {
    __shared__ int csum[256];
    __shared__ int bins[256];
    __shared__ int sel_c, rem_c;
    const int t = threadIdx.x;
    const int target = (phase == 0) ? kkeep : state[1];
    int s = 0;
    const int* h = hist + t * 256;
    for (int i = 0; i < 256; i++) s += h[i];
    csum[t] = s;
    __syncthreads();
    if (t == 0) {
        int acc = 0; int c = 255;
        for (; c > 0; c--) {
            if (acc + csum[c] >= target) break;
            acc += csum[c];
        }
        sel_c = c; rem_c = target - acc;
    }
    __syncthreads();
    bins[t] = hist[sel_c * 256 + t];
    __syncthreads();
    if (t == 0) {
        int rem = rem_c;
        int acc = 0; int b = 255;
        for (; b > 0; b--) {
            if (acc + bins[b] >= rem) break;
            acc += bins[b];
        }
        int bucket = sel_c * 256 + b;
        if (phase == 0) { state[0] = bucket; state[1] = rem - acc; }
        else            { state[2] = (int)(((unsigned)state[0] << 16) | (unsigned)bucket); }
    }
}

__global__ void prune_mask(float* __restrict__ x, const float* __restrict__ imp,
                           const int* __restrict__ state, int n) {
    const unsigned K = (unsigned)state[2];
    int i = blockIdx.x * blockDim.x + threadIdx.x;
    if (i >= n) return;
    float im = imp[i];
    float mult = (__float_as_uint(im) >= K) ? im : 0.f;
#pragma unroll
    for (int c = 0; c < 16; c++) x[(size_t)i * 16 + c] *= mult;
}

extern "C" void kernel_launch(void* const* d_in, const int* in_sizes, int n_in,
                              void* d_out, int out_size, void* d_ws, size_t ws_size,
                              hipStream_t stream) {
    const float* vf    = (const float*)d_in[0];
    const float* W_in  = (const float*)d_in[1];
    const float* g_in  = (const float*)d_in[2];
    const float* b_in  = (const float*)d_in[3];
    const float* Wb1   = (const float*)d_in[4];
    const float* gb1   = (const float*)d_in[6];
    const float* beb1  = (const float*)d_in[7];
    const float* Wp    = (const float*)d_in[8];
    const float* Wd    = (const float*)d_in[9];
    const float* g_d   = (const float*)d_in[10];
    const float* b_d   = (const float*)d_in[11];
    const float* Wb2   = (const float*)d_in[12];
    const float* gb2   = (const float*)d_in[14];
    const float* beb2  = (const float*)d_in[15];
    const int* rb1_in  = (const int*)d_in[16];
    const int* rb1_out = (const int*)d_in[17];
    const int* rbd_in  = (const int*)d_in[18];
    const int* rbd_out = (const int*)d_in[19];
    const int* rb2_in  = (const int*)d_in[20];
    const int* rb2_out = (const int*)d_in[21];

    const int N  = in_sizes[0] / 5;
    const int P1 = in_sizes[16] / 27;
    const int Pd = in_sizes[18] / 27;
    const int P2 = in_sizes[20] / 27;
    const int n2 = out_size / 32;
    const int kkeep = N - N / 2;

    // workspace layout (floats); every region 16B-aligned (sizes padded to x4)
    auto pad4 = [](size_t v) { return (v + 3) & ~(size_t)3; };
    float* A     = (float*)d_ws;                       // N x 16
    float* B     = A   + pad4((size_t)N * 16);         // N x 16
    float* imp   = B   + pad4((size_t)N * 16);         // N
    float* D     = imp + pad4((size_t)N);              // n2 x 32 (stage-2 skip)
    float* E     = D   + pad4((size_t)n2 * 32);        // n2 x 32 (first: invd ints)
    float* stats = E   + pad4((size_t)n2 * 32);        // 64
    int*   cnt1  = (int*)(stats + 64);
    int*   cntd  = cnt1 + 32;
    int*   cnt2  = cntd + 32;
    int*   hist  = cnt2 + 32;                          // 65536
    int*   state = hist + 65536;
    int*   invd  = (int*)E;                            // 27 * n2 ints (<= E size)
    float* OUT   = (float*)d_out;
    float* C2    = OUT;                                // stage-1 conv scratch (16N <= 32n2)

    const int gs1 = (N + 255) / 256;
    const int gs2 = (n2 + 255) / 256;
    const int gew = 2048;

    rb_count_kernel<<<1, 32, 0, stream>>>(rb1_out, P1, N,  cnt1);
    rb_count_kernel<<<1, 32, 0, stream>>>(rbd_out, Pd, n2, cntd);
    rb_count_kernel<<<1, 32, 0, stream>>>(rb2_out, P2, n2, cnt2);

    // ---- conv_input: (N,5)->(N,16), BN, ReLU -> A
    conv_gather_sorted<5, 16><<<gs1, 256, 0, stream>>>(vf, W_in, rb1_in, rb1_out, cnt1, P1, N, B);
    hipMemsetAsync(stats, 0, 64 * 4, stream);
    bn_stats<16><<<512, 256, 0, stream>>>(B, N, stats);
    bn_apply<16, true><<<gew, 256, 0, stream>>>(B, stats, g_in, b_in, N, A);

    // ---- conv1: 2x SparseBasicBlock @16
    for (int i = 0; i < 2; i++) {
        const float* W0 = Wb1 + (size_t)(i * 2 + 0) * 27 * 256;
        const float* W1 = Wb1 + (size_t)(i * 2 + 1) * 27 * 256;
        conv_gather_sorted<16, 16><<<gs1, 256, 0, stream>>>(A, W0, rb1_in, rb1_out, cnt1, P1, N, B);
        hipMemsetAsync(stats, 0, 64 * 4, stream);
        bn_stats<16><<<512, 256, 0, stream>>>(B, N, stats);
        bn_apply<16, true><<<gew, 256, 0, stream>>>(B, stats, gb1 + (i * 2 + 0) * 16, beb1 + (i * 2 + 0) * 16, N, B);
        conv_gather_sorted<16, 16><<<gs1, 256, 0, stream>>>(B, W1, rb1_in, rb1_out, cnt1, P1, N, C2);
        hipMemsetAsync(stats, 0, 64 * 4, stream);
        bn_stats<16><<<512, 256, 0, stream>>>(C2, N, stats);
        bn_apply_addrelu<16><<<gew, 256, 0, stream>>>(C2, A, stats, gb1 + (i * 2 + 1) * 16, beb1 + (i * 2 + 1) * 16, N, A);
    }

    // ---- pruning: imp = sigmoid(conv 16->1); exact top-k threshold; mask A
    conv_gather_sorted<16, 1><<<gs1, 256, 0, stream>>>(A, Wp, rb1_in, rb1_out, cnt1, P1, N, imp);
    sigmoid_k<<<(N + 255) / 256, 256, 0, stream>>>(imp, N);
    hipMemsetAsync(hist, 0, 65536 * 4, stream);
    hist_hi<<<512, 256, 0, stream>>>(imp, N, hist);
    scan_sel<<<1, 256, 0, stream>>>(hist, kkeep, 0, state);
    hipMemsetAsync(hist, 0, 65536 * 4, stream);
    hist_lo<<<512, 256, 0, stream>>>(imp, N, state, hist);
    scan_sel<<<1, 256, 0, stream>>>(hist, kkeep, 1, state);
    prune_mask<<<(N + 255) / 256, 256, 0, stream>>>(A, imp, state, N);

    // ---- strided downsample 16->32 (dense inverse map in E region) + BN + ReLU -> D
    hipMemsetAsync(invd, 0xFF, (size_t)27 * n2 * 4, stream);
    inv_build<<<dim3((Pd + 255) / 256, 27), 256, 0, stream>>>(rbd_in, rbd_out, cntd, Pd, n2, invd);
    conv_gather_inv<16, 32><<<gs2, 256, 0, stream>>>(A, Wd, invd, n2, D);
    hipMemsetAsync(stats, 0, 64 * 4, stream);
    bn_stats<32><<<512, 256, 0, stream>>>(D, n2, stats);
    bn_apply<32, true><<<gew, 256, 0, stream>>>(D, stats, g_d, b_d, n2, D);

    // ---- conv2: 2x SparseBasicBlock @32  (invd dead -> E reused as float buf)
    for (int i = 0; i < 2; i++) {
        const float* W0 = Wb2 + (size_t)(i * 2 + 0) * 27 * 1024;
        const float* W1 = Wb2 + (size_t)(i * 2 + 1) * 27 * 1024;
        conv_gather_sorted<32, 32><<<gs2, 256, 0, stream>>>(D, W0, rb2_in, rb2_out, cnt2, P2, n2, E);
        hipMemsetAsync(stats, 0, 64 * 4, stream);
        bn_stats<32><<<512, 256, 0, stream>>>(E, n2, stats);
        bn_apply<32, true><<<gew, 256, 0, stream>>>(E, stats, gb2 + (i * 2 + 0) * 32, beb2 + (i * 2 + 0) * 32, n2, E);
        conv_gather_sorted<32, 32><<<gs2, 256, 0, stream>>>(E, W1, rb2_in, rb2_out, cnt2, P2, n2, OUT);
        hipMemsetAsync(stats, 0, 64 * 4, stream);
        bn_stats<32><<<512, 256, 0, stream>>>(OUT, n2, stats);
        bn_apply_addrelu<32><<<gew, 256, 0, stream>>>(OUT, D, stats, gb2 + (i * 2 + 1) * 32, beb2 + (i * 2 + 1) * 32, n2, (i == 0) ? D : OUT);
    }
}

// Round 3
// 3371.093 us; speedup vs baseline: 14.6533x; 1.0550x over previous
//
#include <hip/hip_runtime.h>

// ---------------------------------------------------------------------------
// Sparse 3D conv backbone — fp32 gather, no conv atomics.
//   conv_input (5->16, rb1) + BN + ReLU
//   2x BasicBlock @16 (rb1)
//   pruning: imp=sigmoid(conv 16->1), exact top-k(N/2) threshold mask
//   strided conv 16->32 (rbd, dense inverse map) + BN + ReLU
//   2x BasicBlock @32 (rb2)  -> d_out (n2 x 32)
// Round-3 changes: per-k LDS inverse map (LDS 32KB->6.5KB, occupancy 2x),
// precomputed segment boundaries (seg_build), BN-stats fused into conv
// epilogue, sigmoid fused into Wp conv.
// ---------------------------------------------------------------------------

__global__ void rb_count_kernel(const int* __restrict__ rout, int P, int n_out,
                                int* __restrict__ cnt) {
    int k = threadIdx.x;
    if (k >= 27) return;
    const int* r = rout + (size_t)k * P;
    int lo = 0, hi = P;              // first index with r[i] >= n_out (sentinel)
    while (lo < hi) {
        int mid = (lo + hi) >> 1;
        if (r[mid] < n_out) lo = mid + 1; else hi = mid;
    }
    cnt[k] = lo;
}

// segment boundaries per (k, 256-output block): segs[k][b] = lower_bound(rout[k], b*256)
__global__ void seg_build(const int* __restrict__ rout, const int* __restrict__ cnt,
                          int P, int nb, int* __restrict__ segs) {
    const int k = blockIdx.y;
    const int b = blockIdx.x * 256 + threadIdx.x;
    if (b > nb) return;
    const int target = b * 256;
    const int* r = rout + (size_t)k * P;
    int lo = 0, hi = cnt[k];
    while (lo < hi) {
        int m = (lo + hi) >> 1;
        if (r[m] < target) lo = m + 1; else hi = m;
    }
    segs[k * (nb + 1) + b] = lo;
}

__global__ void inv_build(const int* __restrict__ rin, const int* __restrict__ rout,
                          const int* __restrict__ cnt, int P, int n_out,
                          int* __restrict__ inv) {
    const int k = blockIdx.y;
    const int p = blockIdx.x * 256 + threadIdx.x;
    if (p < cnt[k])
        inv[(size_t)k * n_out + rout[(size_t)k * P + p]] = rin[(size_t)k * P + p];
}

// ---- gather conv for sorted-unique rulebooks (rb1, rb2) -------------------
template <int CIN, int COUT, bool SIGMOID, bool STATS>
__global__ __launch_bounds__(256) void conv_gather(
        const float* __restrict__ feat, const float* __restrict__ W,
        const int* __restrict__ rin, const int* __restrict__ rout,
        const int* __restrict__ segs, int P, int n_out,
        float* __restrict__ out, float* __restrict__ stats) {
    __shared__ float Ws[CIN * COUT];
    __shared__ int invl[256];
    __shared__ int seg[54];
    __shared__ float part[2][4][COUT];
    const int t = threadIdx.x;
    const int j0 = blockIdx.x * 256;
    const int nb1 = gridDim.x + 1;
    if (t < 54) seg[t] = segs[(t >> 1) * nb1 + blockIdx.x + (t & 1)];
    float acc[COUT];
#pragma unroll
    for (int co = 0; co < COUT; co++) acc[co] = 0.f;
    __syncthreads();

    for (int k = 0; k < 27; k++) {
        const int s0 = seg[2 * k], s1 = seg[2 * k + 1];
        if (s0 == s1) continue;                   // block-uniform skip
        invl[t] = -1;
        __syncthreads();
        const int idx = s0 + t;                   // segment length <= 256 (unique routs)
        if (idx < s1)
            invl[rout[(size_t)k * P + idx] - j0] = rin[(size_t)k * P + idx];
        for (int i = t; i < CIN * COUT; i += 256) Ws[i] = W[k * CIN * COUT + i];
        __syncthreads();
        const int in = invl[t];
        if (in >= 0) {
            const float* fr = feat + (size_t)in * CIN;
            if constexpr (CIN % 4 == 0) {
#pragma unroll
                for (int q = 0; q < CIN / 4; q++) {
                    const float4 v = *(const float4*)(fr + 4 * q);
                    const float fv[4] = {v.x, v.y, v.z, v.w};
#pragma unroll
                    for (int u = 0; u < 4; u++)
#pragma unroll
                        for (int co = 0; co < COUT; co++)
                            acc[co] += fv[u] * Ws[(4 * q + u) * COUT + co];
                }
            } else {
#pragma unroll
                for (int ci = 0; ci < CIN; ci++) {
                    const float fv = fr[ci];
#pragma unroll
                    for (int co = 0; co < COUT; co++)
                        acc[co] += fv * Ws[ci * COUT + co];
                }
            }
        }
    }

    const int j = j0 + t;
    if (j < n_out) {
#pragma unroll
        for (int co = 0; co < COUT; co++) {
            float v = acc[co];
            if (SIGMOID) v = 1.f / (1.f + expf(-v));
            out[(size_t)j * COUT + co] = v;
        }
    }
    if (STATS) {   // fused BN statistics (tail threads hold acc==0)
        const int wv = t >> 6, lane = t & 63;
#pragma unroll
        for (int co = 0; co < COUT; co++) {
            float s = acc[co], s2 = s * s;
#pragma unroll
            for (int d = 1; d < 64; d <<= 1) {
                s += __shfl_xor(s, d);
                s2 += __shfl_xor(s2, d);
            }
            if (lane == 0) { part[0][wv][co] = s; part[1][wv][co] = s2; }
        }
        __syncthreads();
        if (t < 2 * COUT) {
            const int which = t / COUT, co = t - which * COUT;
            atomicAdd(&stats[which * COUT + co],
                      part[which][0][co] + part[which][1][co] +
                      part[which][2][co] + part[which][3][co]);
        }
    }
}

// ---- gather conv via dense inverse map (strided rulebook) -----------------
template <int CIN, int COUT>
__global__ __launch_bounds__(256) void conv_gather_inv(
        const float* __restrict__ feat, const float* __restrict__ W,
        const int* __restrict__ inv, int n_out,
        float* __restrict__ out, float* __restrict__ stats) {
    __shared__ float Ws[CIN * COUT];
    __shared__ float part[2][4][COUT];
    const int t = threadIdx.x;
    const int j = blockIdx.x * 256 + t;
    float acc[COUT];
#pragma unroll
    for (int co = 0; co < COUT; co++) acc[co] = 0.f;
    for (int k = 0; k < 27; k++) {
        __syncthreads();
        for (int i = t; i < CIN * COUT; i += 256) Ws[i] = W[k * CIN * COUT + i];
        __syncthreads();
        const int in = (j < n_out) ? inv[(size_t)k * n_out + j] : -1;
        if (in >= 0) {
            const float* fr = feat + (size_t)in * CIN;
#pragma unroll
            for (int q = 0; q < CIN / 4; q++) {
                const float4 v = *(const float4*)(fr + 4 * q);
                const float fv[4] = {v.x, v.y, v.z, v.w};
#pragma unroll
                for (int u = 0; u < 4; u++)
#pragma unroll
                    for (int co = 0; co < COUT; co++)
                        acc[co] += fv[u] * Ws[(4 * q + u) * COUT + co];
            }
        }
    }
    if (j < n_out) {
#pragma unroll
        for (int co = 0; co < COUT; co++) out[(size_t)j * COUT + co] = acc[co];
    }
    const int wv = t >> 6, lane = t & 63;
#pragma unroll
    for (int co = 0; co < COUT; co++) {
        float s = acc[co], s2 = s * s;
#pragma unroll
        for (int d = 1; d < 64; d <<= 1) {
            s += __shfl_xor(s, d);
            s2 += __shfl_xor(s2, d);
        }
        if (lane == 0) { part[0][wv][co] = s; part[1][wv][co] = s2; }
    }
    __syncthreads();
    if (t < 2 * COUT) {
        const int which = t / COUT, co = t - which * COUT;
        atomicAdd(&stats[which * COUT + co],
                  part[which][0][co] + part[which][1][co] +
                  part[which][2][co] + part[which][3][co]);
    }
}

template <int C, bool RELU>
__global__ void bn_apply(const float* __restrict__ x, const float* __restrict__ stats,
                         const float* __restrict__ gg, const float* __restrict__ bb,
                         int n, float* __restrict__ y) {
    const float nf = (float)n;
    const long long total = (long long)n * C;
    for (long long idx = (long long)blockIdx.x * blockDim.x + threadIdx.x;
         idx < total; idx += (long long)gridDim.x * blockDim.x) {
        int ch = (int)(idx & (C - 1));
        float m = stats[ch] / nf;
        float v = stats[C + ch] / nf - m * m;
        float r = rsqrtf(v + 1e-3f);
        float val = gg[ch] * (x[idx] - m) * r + bb[ch];
        if (RELU) val = fmaxf(val, 0.f);
        y[idx] = val;
    }
}

template <int C>
__global__ void bn_apply_addrelu(const float* __restrict__ x,
                                 const float* __restrict__ skip,
                                 const float* __restrict__ stats,
                                 const float* __restrict__ gg,
                                 const float* __restrict__ bb,
                                 int n, float* __restrict__ y) {
    const float nf = (float)n;
    const long long total = (long long)n * C;
    for (long long idx = (long long)blockIdx.x * blockDim.x + threadIdx.x;
         idx < total; idx += (long long)gridDim.x * blockDim.x) {
        int ch = (int)(idx & (C - 1));
        float m = stats[ch] / nf;
        float v = stats[C + ch] / nf - m * m;
        float r = rsqrtf(v + 1e-3f);
        float val = gg[ch] * (x[idx] - m) * r + bb[ch] + skip[idx];
        y[idx] = fmaxf(val, 0.f);
    }
}

__global__ void hist_hi(const float* __restrict__ imp, int n, int* __restrict__ hist) {
    for (int i = blockIdx.x * blockDim.x + threadIdx.x; i < n;
         i += gridDim.x * blockDim.x) {
        unsigned b = __float_as_uint(imp[i]) >> 16;
        atomicAdd(&hist[b], 1);
    }
}

__global__ void hist_lo(const float* __restrict__ imp, int n,
                        const int* __restrict__ state, int* __restrict__ hist) {
    unsigned hb = (unsigned)state[0];
    for (int i = blockIdx.x * blockDim.x + threadIdx.x; i < n;
         i += gridDim.x * blockDim.x) {
        unsigned b = __float_as_uint(imp[i]);
        if ((b >> 16) == hb) atomicAdd(&hist[b & 0xffffu], 1);
    }
}

__global__ __launch_bounds__(256) void scan_sel(const int* __restrict__ hist,
                                                int kkeep, int phase,
                                                int* __restrict__ state) {
    __shared__ int csum[256];
    __shared__ int bins[256];
    __shared__ int sel_c, rem_c;
    const int t = threadIdx.x;
    const int target = (phase == 0) ? kkeep : state[1];
    int s = 0;
    const int* h = hist + t * 256;
    for (int i = 0; i < 256; i++) s += h[i];
    csum[t] = s;
    __syncthreads();
    if (t == 0) {
        int acc = 0; int c = 255;
        for (; c > 0; c--) {
            if (acc + csum[c] >= target) break;
            acc += csum[c];
        }
        sel_c = c; rem_c = target - acc;
    }
    __syncthreads();
    bins[t] = hist[sel_c * 256 + t];
    __syncthreads();
    if (t == 0) {
        int rem = rem_c;
        int acc = 0; int b = 255;
        for (; b > 0; b--) {
            if (acc + bins[b] >= rem) break;
            acc += bins[b];
        }
        int bucket = sel_c * 256 + b;
        if (phase == 0) { state[0] = bucket; state[1] = rem - acc; }
        else            { state[2] = (int)(((unsigned)state[0] << 16) | (unsigned)bucket); }
    }
}

__global__ void prune_mask(float* __restrict__ x, const float* __restrict__ imp,
                           const int* __restrict__ state, int n) {
    const unsigned K = (unsigned)state[2];
    int i = blockIdx.x * blockDim.x + threadIdx.x;
    if (i >= n) return;
    float im = imp[i];
    float mult = (__float_as_uint(im) >= K) ? im : 0.f;
#pragma unroll
    for (int c = 0; c < 16; c++) x[(size_t)i * 16 + c] *= mult;
}

extern "C" void kernel_launch(void* const* d_in, const int* in_sizes, int n_in,
                              void* d_out, int out_size, void* d_ws, size_t ws_size,
                              hipStream_t stream) {
    const float* vf    = (const float*)d_in[0];
    const float* W_in  = (const float*)d_in[1];
    const float* g_in  = (const float*)d_in[2];
    const float* b_in  = (const float*)d_in[3];
    const float* Wb1   = (const float*)d_in[4];
    const float* gb1   = (const float*)d_in[6];
    const float* beb1  = (const float*)d_in[7];
    const float* Wp    = (const float*)d_in[8];
    const float* Wd    = (const float*)d_in[9];
    const float* g_d   = (const float*)d_in[10];
    const float* b_d   = (const float*)d_in[11];
    const float* Wb2   = (const float*)d_in[12];
    const float* gb2   = (const float*)d_in[14];
    const float* beb2  = (const float*)d_in[15];
    const int* rb1_in  = (const int*)d_in[16];
    const int* rb1_out = (const int*)d_in[17];
    const int* rbd_in  = (const int*)d_in[18];
    const int* rbd_out = (const int*)d_in[19];
    const int* rb2_in  = (const int*)d_in[20];
    const int* rb2_out = (const int*)d_in[21];

    const int N  = in_sizes[0] / 5;
    const int P1 = in_sizes[16] / 27;
    const int Pd = in_sizes[18] / 27;
    const int P2 = in_sizes[20] / 27;
    const int n2 = out_size / 32;
    const int kkeep = N - N / 2;

    const int gs1 = (N + 255) / 256;     // 256-output blocks over N
    const int gs2 = (n2 + 255) / 256;    // over n2
    const int gew = 2048;

    // workspace layout (floats); regions 16B-aligned
    auto pad4 = [](size_t v) { return (v + 3) & ~(size_t)3; };
    float* A     = (float*)d_ws;                       // N x 16
    float* B     = A   + pad4((size_t)N * 16);         // N x 16
    float* imp   = B   + pad4((size_t)N * 16);         // N
    float* D     = imp + pad4((size_t)N);              // n2 x 32 (stage-2 skip)
    float* E     = D   + pad4((size_t)n2 * 32);        // n2 x 32 (first: invd ints)
    float* stats = E   + pad4((size_t)n2 * 32);        // 64
    int*   cnt1  = (int*)(stats + 64);
    int*   cntd  = cnt1 + 32;
    int*   cnt2  = cntd + 32;
    int*   hist  = cnt2 + 32;                          // 65536
    int*   state = hist + 65536;                       // 8
    int*   segs1 = state + 8;                          // 27 * (gs1+1)
    int*   segs2 = segs1 + 27 * (gs1 + 1);             // 27 * (gs2+1)
    int*   invd  = (int*)E;                            // 27 * n2 ints (<= E)
    float* OUT   = (float*)d_out;
    float* C2    = OUT;                                // stage-1 scratch (16N <= 32n2)

    rb_count_kernel<<<1, 32, 0, stream>>>(rb1_out, P1, N,  cnt1);
    rb_count_kernel<<<1, 32, 0, stream>>>(rbd_out, Pd, n2, cntd);
    rb_count_kernel<<<1, 32, 0, stream>>>(rb2_out, P2, n2, cnt2);
    seg_build<<<dim3((gs1 + 256) / 256, 27), 256, 0, stream>>>(rb1_out, cnt1, P1, gs1, segs1);
    seg_build<<<dim3((gs2 + 256) / 256, 27), 256, 0, stream>>>(rb2_out, cnt2, P2, gs2, segs2);

    // ---- conv_input: (N,5)->(N,16) [+stats], BN+ReLU -> A
    hipMemsetAsync(stats, 0, 64 * 4, stream);
    conv_gather<5, 16, false, true><<<gs1, 256, 0, stream>>>(vf, W_in, rb1_in, rb1_out, segs1, P1, N, B, stats);
    bn_apply<16, true><<<gew, 256, 0, stream>>>(B, stats, g_in, b_in, N, A);

    // ---- conv1: 2x SparseBasicBlock @16
    for (int i = 0; i < 2; i++) {
        const float* W0 = Wb1 + (size_t)(i * 2 + 0) * 27 * 256;
        const float* W1 = Wb1 + (size_t)(i * 2 + 1) * 27 * 256;
        hipMemsetAsync(stats, 0, 64 * 4, stream);
        conv_gather<16, 16, false, true><<<gs1, 256, 0, stream>>>(A, W0, rb1_in, rb1_out, segs1, P1, N, B, stats);
        bn_apply<16, true><<<gew, 256, 0, stream>>>(B, stats, gb1 + (i * 2 + 0) * 16, beb1 + (i * 2 + 0) * 16, N, B);
        hipMemsetAsync(stats, 0, 64 * 4, stream);
        conv_gather<16, 16, false, true><<<gs1, 256, 0, stream>>>(B, W1, rb1_in, rb1_out, segs1, P1, N, C2, stats);
        bn_apply_addrelu<16><<<gew, 256, 0, stream>>>(C2, A, stats, gb1 + (i * 2 + 1) * 16, beb1 + (i * 2 + 1) * 16, N, A);
    }

    // ---- pruning: imp = sigmoid(conv 16->1) fused; exact top-k; mask A
    conv_gather<16, 1, true, false><<<gs1, 256, 0, stream>>>(A, Wp, rb1_in, rb1_out, segs1, P1, N, imp, stats);
    hipMemsetAsync(hist, 0, 65536 * 4, stream);
    hist_hi<<<512, 256, 0, stream>>>(imp, N, hist);
    scan_sel<<<1, 256, 0, stream>>>(hist, kkeep, 0, state);
    hipMemsetAsync(hist, 0, 65536 * 4, stream);
    hist_lo<<<512, 256, 0, stream>>>(imp, N, state, hist);
    scan_sel<<<1, 256, 0, stream>>>(hist, kkeep, 1, state);
    prune_mask<<<(N + 255) / 256, 256, 0, stream>>>(A, imp, state, N);

    // ---- strided downsample 16->32 (dense inverse map) + BN + ReLU -> D
    hipMemsetAsync(invd, 0xFF, (size_t)27 * n2 * 4, stream);
    inv_build<<<dim3((Pd + 255) / 256, 27), 256, 0, stream>>>(rbd_in, rbd_out, cntd, Pd, n2, invd);
    hipMemsetAsync(stats, 0, 64 * 4, stream);
    conv_gather_inv<16, 32><<<gs2, 256, 0, stream>>>(A, Wd, invd, n2, D, stats);
    bn_apply<32, true><<<gew, 256, 0, stream>>>(D, stats, g_d, b_d, n2, D);

    // ---- conv2: 2x SparseBasicBlock @32 (invd dead -> E reused)
    for (int i = 0; i < 2; i++) {
        const float* W0 = Wb2 + (size_t)(i * 2 + 0) * 27 * 1024;
        const float* W1 = Wb2 + (size_t)(i * 2 + 1) * 27 * 1024;
        hipMemsetAsync(stats, 0, 64 * 4, stream);
        conv_gather<32, 32, false, true><<<gs2, 256, 0, stream>>>(D, W0, rb2_in, rb2_out, segs2, P2, n2, E, stats);
        bn_apply<32, true><<<gew, 256, 0, stream>>>(E, stats, gb2 + (i * 2 + 0) * 32, beb2 + (i * 2 + 0) * 32, n2, E);
        hipMemsetAsync(stats, 0, 64 * 4, stream);
        conv_gather<32, 32, false, true><<<gs2, 256, 0, stream>>>(E, W1, rb2_in, rb2_out, segs2, P2, n2, OUT, stats);
        bn_apply_addrelu<32><<<gew, 256, 0, stream>>>(OUT, D, stats, gb2 + (i * 2 + 1) * 32, beb2 + (i * 2 + 1) * 32, n2, (i == 0) ? D : OUT);
    }
}

// Round 4
// 3237.098 us; speedup vs baseline: 15.2598x; 1.0414x over previous
//
#include <hip/hip_runtime.h>

// ---------------------------------------------------------------------------
// Sparse 3D conv backbone — fp32 gather, no conv atomics.
//   conv_input (5->16, rb1) + BN + ReLU
//   2x BasicBlock @16 (rb1)
//   pruning: imp=sigmoid(conv 16->1), exact top-k(N/2) threshold mask
//   strided conv 16->32 (rbd, dense inverse map) + BN + ReLU
//   2x BasicBlock @32 (rb2)  -> d_out (n2 x 32)
// Round-4 changes: weights read as wave-uniform global loads (-> SGPR/s_load,
// no LDS weight staging, no per-k weight barrier); tag-based int2 inverse map
// (no per-k clear); FMA region kept uniform (predicated gather into f[]=0).
// ---------------------------------------------------------------------------

__global__ void rb_count_kernel(const int* __restrict__ rout, int P, int n_out,
                                int* __restrict__ cnt) {
    int k = threadIdx.x;
    if (k >= 27) return;
    const int* r = rout + (size_t)k * P;
    int lo = 0, hi = P;              // first index with r[i] >= n_out (sentinel)
    while (lo < hi) {
        int mid = (lo + hi) >> 1;
        if (r[mid] < n_out) lo = mid + 1; else hi = mid;
    }
    cnt[k] = lo;
}

// segment boundaries per (k, 256-output block): segs[k][b] = lower_bound(rout[k], b*256)
__global__ void seg_build(const int* __restrict__ rout, const int* __restrict__ cnt,
                          int P, int nb, int* __restrict__ segs) {
    const int k = blockIdx.y;
    const int b = blockIdx.x * 256 + threadIdx.x;
    if (b > nb) return;
    const int target = b * 256;
    const int* r = rout + (size_t)k * P;
    int lo = 0, hi = cnt[k];
    while (lo < hi) {
        int m = (lo + hi) >> 1;
        if (r[m] < target) lo = m + 1; else hi = m;
    }
    segs[k * (nb + 1) + b] = lo;
}

__global__ void inv_build(const int* __restrict__ rin, const int* __restrict__ rout,
                          const int* __restrict__ cnt, int P, int n_out,
                          int* __restrict__ inv) {
    const int k = blockIdx.y;
    const int p = blockIdx.x * 256 + threadIdx.x;
    if (p < cnt[k])
        inv[(size_t)k * n_out + rout[(size_t)k * P + p]] = rin[(size_t)k * P + p];
}

// ---- gather conv for sorted-unique rulebooks (rb1, rb2) -------------------
template <int CIN, int COUT, bool SIGMOID, bool STATS>
__global__ __launch_bounds__(256) void conv_gather(
        const float* __restrict__ feat, const float* __restrict__ W,
        const int* __restrict__ rin, const int* __restrict__ rout,
        const int* __restrict__ segs, int P, int n_out,
        float* __restrict__ out, float* __restrict__ stats) {
    __shared__ int2 invl[256];        // {tag k, rin}; valid iff tag == k
    __shared__ int seg[54];
    __shared__ float part[2][4][COUT];
    const int t = threadIdx.x;
    const int j0 = blockIdx.x * 256;
    const int nb1 = gridDim.x + 1;
    if (t < 54) seg[t] = segs[(t >> 1) * nb1 + blockIdx.x + (t & 1)];
    invl[t] = make_int2(-1, -1);
    float acc[COUT];
#pragma unroll
    for (int co = 0; co < COUT; co++) acc[co] = 0.f;
    __syncthreads();

    for (int k = 0; k < 27; k++) {
        const int s0 = seg[2 * k], s1 = seg[2 * k + 1];
        if (s0 == s1) continue;                   // block-uniform skip
        const int idx = s0 + t;                   // segment length <= 256
        if (idx < s1)
            invl[rout[(size_t)k * P + idx] - j0] = make_int2(k, rin[(size_t)k * P + idx]);
        __syncthreads();
        const int2 e = invl[t];
        const int in = (e.x == k) ? e.y : -1;
        __syncthreads();                          // reads done before next scatter

        float f[CIN];
#pragma unroll
        for (int ci = 0; ci < CIN; ci++) f[ci] = 0.f;
        if (in >= 0) {                            // predicated gather; FMA stays uniform
            const float* fr = feat + (size_t)in * CIN;
            if constexpr (CIN % 4 == 0) {
#pragma unroll
                for (int q = 0; q < CIN / 4; q++) {
                    const float4 v = *(const float4*)(fr + 4 * q);
                    f[4 * q] = v.x; f[4 * q + 1] = v.y;
                    f[4 * q + 2] = v.z; f[4 * q + 3] = v.w;
                }
            } else {
#pragma unroll
                for (int ci = 0; ci < CIN; ci++) f[ci] = fr[ci];
            }
        }
        const float* __restrict__ Wk = W + k * CIN * COUT;   // lane-uniform -> s_load
#pragma unroll
        for (int ci = 0; ci < CIN; ci++) {
            const float fv = f[ci];
#pragma unroll
            for (int co = 0; co < COUT; co++)
                acc[co] = fmaf(fv, Wk[ci * COUT + co], acc[co]);
        }
    }

    const int j = j0 + t;
    if (j < n_out) {
#pragma unroll
        for (int co = 0; co < COUT; co++) {
            float v = acc[co];
            if (SIGMOID) v = 1.f / (1.f + expf(-v));
            out[(size_t)j * COUT + co] = v;
        }
    }
    if (STATS) {   // fused BN statistics (tail threads hold acc==0)
        const int wv = t >> 6, lane = t & 63;
#pragma unroll
        for (int co = 0; co < COUT; co++) {
            float s = acc[co], s2 = s * s;
#pragma unroll
            for (int d = 1; d < 64; d <<= 1) {
                s += __shfl_xor(s, d);
                s2 += __shfl_xor(s2, d);
            }
            if (lane == 0) { part[0][wv][co] = s; part[1][wv][co] = s2; }
        }
        __syncthreads();
        if (t < 2 * COUT) {
            const int which = t / COUT, co = t - which * COUT;
            atomicAdd(&stats[which * COUT + co],
                      part[which][0][co] + part[which][1][co] +
                      part[which][2][co] + part[which][3][co]);
        }
    }
}

// ---- gather conv via dense inverse map (strided rulebook) -----------------
template <int CIN, int COUT>
__global__ __launch_bounds__(256) void conv_gather_inv(
        const float* __restrict__ feat, const float* __restrict__ W,
        const int* __restrict__ inv, int n_out,
        float* __restrict__ out, float* __restrict__ stats) {
    __shared__ float part[2][4][COUT];
    const int t = threadIdx.x;
    const int j = blockIdx.x * 256 + t;
    float acc[COUT];
#pragma unroll
    for (int co = 0; co < COUT; co++) acc[co] = 0.f;
    for (int k = 0; k < 27; k++) {
        const int in = (j < n_out) ? inv[(size_t)k * n_out + j] : -1;
        float f[CIN];
#pragma unroll
        for (int ci = 0; ci < CIN; ci++) f[ci] = 0.f;
        if (in >= 0) {
            const float* fr = feat + (size_t)in * CIN;
#pragma unroll
            for (int q = 0; q < CIN / 4; q++) {
                const float4 v = *(const float4*)(fr + 4 * q);
                f[4 * q] = v.x; f[4 * q + 1] = v.y;
                f[4 * q + 2] = v.z; f[4 * q + 3] = v.w;
            }
        }
        const float* __restrict__ Wk = W + k * CIN * COUT;   // lane-uniform -> s_load
#pragma unroll
        for (int ci = 0; ci < CIN; ci++) {
            const float fv = f[ci];
#pragma unroll
            for (int co = 0; co < COUT; co++)
                acc[co] = fmaf(fv, Wk[ci * COUT + co], acc[co]);
        }
    }
    if (j < n_out) {
#pragma unroll
        for (int co = 0; co < COUT; co++) out[(size_t)j * COUT + co] = acc[co];
    }
    const int wv = t >> 6, lane = t & 63;
#pragma unroll
    for (int co = 0; co < COUT; co++) {
        float s = acc[co], s2 = s * s;
#pragma unroll
        for (int d = 1; d < 64; d <<= 1) {
            s += __shfl_xor(s, d);
            s2 += __shfl_xor(s2, d);
        }
        if (lane == 0) { part[0][wv][co] = s; part[1][wv][co] = s2; }
    }
    __syncthreads();
    if (t < 2 * COUT) {
        const int which = t / COUT, co = t - which * COUT;
        atomicAdd(&stats[which * COUT + co],
                  part[which][0][co] + part[which][1][co] +
                  part[which][2][co] + part[which][3][co]);
    }
}

template <int C, bool RELU>
__global__ void bn_apply(const float* __restrict__ x, const float* __restrict__ stats,
                         const float* __restrict__ gg, const float* __restrict__ bb,
                         int n, float* __restrict__ y) {
    const float nf = (float)n;
    const long long total = (long long)n * C;
    for (long long idx = (long long)blockIdx.x * blockDim.x + threadIdx.x;
         idx < total; idx += (long long)gridDim.x * blockDim.x) {
        int ch = (int)(idx & (C - 1));
        float m = stats[ch] / nf;
        float v = stats[C + ch] / nf - m * m;
        float r = rsqrtf(v + 1e-3f);
        float val = gg[ch] * (x[idx] - m) * r + bb[ch];
        if (RELU) val = fmaxf(val, 0.f);
        y[idx] = val;
    }
}

template <int C>
__global__ void bn_apply_addrelu(const float* __restrict__ x,
                                 const float* __restrict__ skip,
                                 const float* __restrict__ stats,
                                 const float* __restrict__ gg,
                                 const float* __restrict__ bb,
                                 int n, float* __restrict__ y) {
    const float nf = (float)n;
    const long long total = (long long)n * C;
    for (long long idx = (long long)blockIdx.x * blockDim.x + threadIdx.x;
         idx < total; idx += (long long)gridDim.x * blockDim.x) {
        int ch = (int)(idx & (C - 1));
        float m = stats[ch] / nf;
        float v = stats[C + ch] / nf - m * m;
        float r = rsqrtf(v + 1e-3f);
        float val = gg[ch] * (x[idx] - m) * r + bb[ch] + skip[idx];
        y[idx] = fmaxf(val, 0.f);
    }
}

__global__ void hist_hi(const float* __restrict__ imp, int n, int* __restrict__ hist) {
    for (int i = blockIdx.x * blockDim.x + threadIdx.x; i < n;
         i += gridDim.x * blockDim.x) {
        unsigned b = __float_as_uint(imp[i]) >> 16;
        atomicAdd(&hist[b], 1);
    }
}

__global__ void hist_lo(const float* __restrict__ imp, int n,
                        const int* __restrict__ state, int* __restrict__ hist) {
    unsigned hb = (unsigned)state[0];
    for (int i = blockIdx.x * blockDim.x + threadIdx.x; i < n;
         i += gridDim.x * blockDim.x) {
        unsigned b = __float_as_uint(imp[i]);
        if ((b >> 16) == hb) atomicAdd(&hist[b & 0xffffu], 1);
    }
}

__global__ __launch_bounds__(256) void scan_sel(const int* __restrict__ hist,
                                                int kkeep, int phase,
                                                int* __restrict__ state) {
    __shared__ int csum[256];
    __shared__ int bins[256];
    __shared__ int sel_c, rem_c;
    const int t = threadIdx.x;
    const int target = (phase == 0) ? kkeep : state[1];
    int s = 0;
    const int* h = hist + t * 256;
    for (int i = 0; i < 256; i++) s += h[i];
    csum[t] = s;
    __syncthreads();
    if (t == 0) {
        int acc = 0; int c = 255;
        for (; c > 0; c--) {
            if (acc + csum[c] >= target) break;
            acc += csum[c];
        }
        sel_c = c; rem_c = target - acc;
    }
    __syncthreads();
    bins[t] = hist[sel_c * 256 + t];
    __syncthreads();
    if (t == 0) {
        int rem = rem_c;
        int acc = 0; int b = 255;
        for (; b > 0; b--) {
            if (acc + bins[b] >= rem) break;
            acc += bins[b];
        }
        int bucket = sel_c * 256 + b;
        if (phase == 0) { state[0] = bucket; state[1] = rem - acc; }
        else            { state[2] = (int)(((unsigned)state[0] << 16) | (unsigned)bucket); }
    }
}

__global__ void prune_mask(float* __restrict__ x, const float* __restrict__ imp,
                           const int* __restrict__ state, int n) {
    const unsigned K = (unsigned)state[2];
    int i = blockIdx.x * blockDim.x + threadIdx.x;
    if (i >= n) return;
    float im = imp[i];
    float mult = (__float_as_uint(im) >= K) ? im : 0.f;
#pragma unroll
    for (int c = 0; c < 16; c++) x[(size_t)i * 16 + c] *= mult;
}

extern "C" void kernel_launch(void* const* d_in, const int* in_sizes, int n_in,
                              void* d_out, int out_size, void* d_ws, size_t ws_size,
                              hipStream_t stream) {
    const float* vf    = (const float*)d_in[0];
    const float* W_in  = (const float*)d_in[1];
    const float* g_in  = (const float*)d_in[2];
    const float* b_in  = (const float*)d_in[3];
    const float* Wb1   = (const float*)d_in[4];
    const float* gb1   = (const float*)d_in[6];
    const float* beb1  = (const float*)d_in[7];
    const float* Wp    = (const float*)d_in[8];
    const float* Wd    = (const float*)d_in[9];
    const float* g_d   = (const float*)d_in[10];
    const float* b_d   = (const float*)d_in[11];
    const float* Wb2   = (const float*)d_in[12];
    const float* gb2   = (const float*)d_in[14];
    const float* beb2  = (const float*)d_in[15];
    const int* rb1_in  = (const int*)d_in[16];
    const int* rb1_out = (const int*)d_in[17];
    const int* rbd_in  = (const int*)d_in[18];
    const int* rbd_out = (const int*)d_in[19];
    const int* rb2_in  = (const int*)d_in[20];
    const int* rb2_out = (const int*)d_in[21];

    const int N  = in_sizes[0] / 5;
    const int P1 = in_sizes[16] / 27;
    const int Pd = in_sizes[18] / 27;
    const int P2 = in_sizes[20] / 27;
    const int n2 = out_size / 32;
    const int kkeep = N - N / 2;

    const int gs1 = (N + 255) / 256;     // 256-output blocks over N
    const int gs2 = (n2 + 255) / 256;    // over n2
    const int gew = 2048;

    // workspace layout (floats); regions 16B-aligned
    auto pad4 = [](size_t v) { return (v + 3) & ~(size_t)3; };
    float* A     = (float*)d_ws;                       // N x 16
    float* B     = A   + pad4((size_t)N * 16);         // N x 16
    float* imp   = B   + pad4((size_t)N * 16);         // N
    float* D     = imp + pad4((size_t)N);              // n2 x 32 (stage-2 skip)
    float* E     = D   + pad4((size_t)n2 * 32);        // n2 x 32 (first: invd ints)
    float* stats = E   + pad4((size_t)n2 * 32);        // 64
    int*   cnt1  = (int*)(stats + 64);
    int*   cntd  = cnt1 + 32;
    int*   cnt2  = cntd + 32;
    int*   hist  = cnt2 + 32;                          // 65536
    int*   state = hist + 65536;                       // 8
    int*   segs1 = state + 8;                          // 27 * (gs1+1)
    int*   segs2 = segs1 + 27 * (gs1 + 1);             // 27 * (gs2+1)
    int*   invd  = (int*)E;                            // 27 * n2 ints (<= E)
    float* OUT   = (float*)d_out;
    float* C2    = OUT;                                // stage-1 scratch (16N <= 32n2)

    rb_count_kernel<<<1, 32, 0, stream>>>(rb1_out, P1, N,  cnt1);
    rb_count_kernel<<<1, 32, 0, stream>>>(rbd_out, Pd, n2, cntd);
    rb_count_kernel<<<1, 32, 0, stream>>>(rb2_out, P2, n2, cnt2);
    seg_build<<<dim3((gs1 + 256) / 256, 27), 256, 0, stream>>>(rb1_out, cnt1, P1, gs1, segs1);
    seg_build<<<dim3((gs2 + 256) / 256, 27), 256, 0, stream>>>(rb2_out, cnt2, P2, gs2, segs2);

    // ---- conv_input: (N,5)->(N,16) [+stats], BN+ReLU -> A
    hipMemsetAsync(stats, 0, 64 * 4, stream);
    conv_gather<5, 16, false, true><<<gs1, 256, 0, stream>>>(vf, W_in, rb1_in, rb1_out, segs1, P1, N, B, stats);
    bn_apply<16, true><<<gew, 256, 0, stream>>>(B, stats, g_in, b_in, N, A);

    // ---- conv1: 2x SparseBasicBlock @16
    for (int i = 0; i < 2; i++) {
        const float* W0 = Wb1 + (size_t)(i * 2 + 0) * 27 * 256;
        const float* W1 = Wb1 + (size_t)(i * 2 + 1) * 27 * 256;
        hipMemsetAsync(stats, 0, 64 * 4, stream);
        conv_gather<16, 16, false, true><<<gs1, 256, 0, stream>>>(A, W0, rb1_in, rb1_out, segs1, P1, N, B, stats);
        bn_apply<16, true><<<gew, 256, 0, stream>>>(B, stats, gb1 + (i * 2 + 0) * 16, beb1 + (i * 2 + 0) * 16, N, B);
        hipMemsetAsync(stats, 0, 64 * 4, stream);
        conv_gather<16, 16, false, true><<<gs1, 256, 0, stream>>>(B, W1, rb1_in, rb1_out, segs1, P1, N, C2, stats);
        bn_apply_addrelu<16><<<gew, 256, 0, stream>>>(C2, A, stats, gb1 + (i * 2 + 1) * 16, beb1 + (i * 2 + 1) * 16, N, A);
    }

    // ---- pruning: imp = sigmoid(conv 16->1) fused; exact top-k; mask A
    conv_gather<16, 1, true, false><<<gs1, 256, 0, stream>>>(A, Wp, rb1_in, rb1_out, segs1, P1, N, imp, stats);
    hipMemsetAsync(hist, 0, 65536 * 4, stream);
    hist_hi<<<512, 256, 0, stream>>>(imp, N, hist);
    scan_sel<<<1, 256, 0, stream>>>(hist, kkeep, 0, state);
    hipMemsetAsync(hist, 0, 65536 * 4, stream);
    hist_lo<<<512, 256, 0, stream>>>(imp, N, state, hist);
    scan_sel<<<1, 256, 0, stream>>>(hist, kkeep, 1, state);
    prune_mask<<<(N + 255) / 256, 256, 0, stream>>>(A, imp, state, N);

    // ---- strided downsample 16->32 (dense inverse map) + BN + ReLU -> D
    hipMemsetAsync(invd, 0xFF, (size_t)27 * n2 * 4, stream);
    inv_build<<<dim3((Pd + 255) / 256, 27), 256, 0, stream>>>(rbd_in, rbd_out, cntd, Pd, n2, invd);
    hipMemsetAsync(stats, 0, 64 * 4, stream);
    conv_gather_inv<16, 32><<<gs2, 256, 0, stream>>>(A, Wd, invd, n2, D, stats);
    bn_apply<32, true><<<gew, 256, 0, stream>>>(D, stats, g_d, b_d, n2, D);

    // ---- conv2: 2x SparseBasicBlock @32 (invd dead -> E reused)
    for (int i = 0; i < 2; i++) {
        const float* W0 = Wb2 + (size_t)(i * 2 + 0) * 27 * 1024;
        const float* W1 = Wb2 + (size_t)(i * 2 + 1) * 27 * 1024;
        hipMemsetAsync(stats, 0, 64 * 4, stream);
        conv_gather<32, 32, false, true><<<gs2, 256, 0, stream>>>(D, W0, rb2_in, rb2_out, segs2, P2, n2, E, stats);
        bn_apply<32, true><<<gew, 256, 0, stream>>>(E, stats, gb2 + (i * 2 + 0) * 32, beb2 + (i * 2 + 0) * 32, n2, E);
        hipMemsetAsync(stats, 0, 64 * 4, stream);
        conv_gather<32, 32, false, true><<<gs2, 256, 0, stream>>>(E, W1, rb2_in, rb2_out, segs2, P2, n2, OUT, stats);
        bn_apply_addrelu<32><<<gew, 256, 0, stream>>>(OUT, D, stats, gb2 + (i * 2 + 1) * 32, beb2 + (i * 2 + 1) * 32, n2, (i == 0) ? D : OUT);
    }
}

// Round 5
// 1925.742 us; speedup vs baseline: 25.6512x; 1.6810x over previous
//
#include <hip/hip_runtime.h>

// ---------------------------------------------------------------------------
// Sparse 3D conv backbone.
// Stage 1 (fp32 VALU, exact vs prior rounds): conv_input 5->16 + BN + ReLU,
//   2x BasicBlock @16 (rb1), prune conv 16->1 + sigmoid + exact top-k mask.
// Stage 2 (bf16 MFMA): strided conv 16->32 (rbd, dense inverse map, 2 taps
//   packed per K=32 MFMA step), 2x BasicBlock @32 (rb2, sorted-segment gather,
//   1 tap per MFMA step), BN-stats fused. d_out = (n2 x 32).
// ---------------------------------------------------------------------------

typedef __attribute__((ext_vector_type(8))) short bf16x8;
typedef __attribute__((ext_vector_type(4))) float f32x4;

static __device__ __forceinline__ unsigned f2bfu(float x) {   // fp32->bf16 RNE
    unsigned b = __float_as_uint(x);
    return (b + 0x7FFFu + ((b >> 16) & 1u)) >> 16;
}

__global__ void rb_count_kernel(const int* __restrict__ rout, int P, int n_out,
                                int* __restrict__ cnt) {
    int k = threadIdx.x;
    if (k >= 27) return;
    const int* r = rout + (size_t)k * P;
    int lo = 0, hi = P;
    while (lo < hi) {
        int mid = (lo + hi) >> 1;
        if (r[mid] < n_out) lo = mid + 1; else hi = mid;
    }
    cnt[k] = lo;
}

// segs[k][b] = lower_bound(rout[k], b*gran), b in [0, nb]
__global__ void seg_build(const int* __restrict__ rout, const int* __restrict__ cnt,
                          int P, int nb, int gran, int* __restrict__ segs) {
    const int k = blockIdx.y;
    const int b = blockIdx.x * 256 + threadIdx.x;
    if (b > nb) return;
    const int target = b * gran;
    const int* r = rout + (size_t)k * P;
    int lo = 0, hi = cnt[k];
    while (lo < hi) {
        int m = (lo + hi) >> 1;
        if (r[m] < target) lo = m + 1; else hi = m;
    }
    segs[k * (nb + 1) + b] = lo;
}

__global__ void inv_build(const int* __restrict__ rin, const int* __restrict__ rout,
                          const int* __restrict__ cnt, int P, int n_out,
                          int* __restrict__ inv) {
    const int k = blockIdx.y;
    const int p = blockIdx.x * 256 + threadIdx.x;
    if (p < cnt[k])
        inv[(size_t)k * n_out + rout[(size_t)k * P + p]] = rin[(size_t)k * P + p];
}

// Pre-pack fp32 weights [T][CI][32] into MFMA B-frag bf16 order:
// pack[((s*2+h)*64+l)*8+j] = W[tap][cin][(l&15)+16h], gk=s*32+(l>>4)*8+j,
// tap=gk/CI, cin=gk%CI, zero if tap>=T.
__global__ void prepack_w(const float* __restrict__ W, int T, int CI, int S,
                          short* __restrict__ pack) {
    int idx = blockIdx.x * 256 + threadIdx.x;     // over S*128
    if (idx >= S * 128) return;
    int l = idx & 63, h = (idx >> 6) & 1, s = idx >> 7;
    int co = (l & 15) + 16 * h;
#pragma unroll
    for (int j = 0; j < 8; j++) {
        int gk = s * 32 + (l >> 4) * 8 + j;
        int tap = gk / CI, cin = gk % CI;
        float w = (tap < T) ? W[((size_t)tap * CI + cin) * 32 + co] : 0.f;
        pack[(size_t)idx * 8 + j] = (short)f2bfu(w);
    }
}

// ---- MFMA gather conv, sorted rulebook, CIN=32 COUT=32 (rb2) --------------
__global__ __launch_bounds__(256) void conv_mfma_sorted32(
        const float* __restrict__ feat, const short* __restrict__ Bp,
        const int* __restrict__ rin, const int* __restrict__ rout,
        const int* __restrict__ segs, int P, int nb16, int n_out,
        float* __restrict__ out, float* __restrict__ stats) {
    __shared__ int invw[64];
    __shared__ float part[2][4][32];
    const int t = threadIdx.x, wv = t >> 6, lane = t & 63;
    const int row = lane & 15, grp = lane >> 4;
    float ss0 = 0.f, qq0 = 0.f, ss1 = 0.f, qq1 = 0.f;

    for (int tile = 0; tile < 4; ++tile) {
        const int rowbase = blockIdx.x * 256 + wv * 64 + tile * 16;
        if (rowbase >= n_out) break;
        const int tix = rowbase >> 4;
        int segv = 0;
        if (lane < 28)      segv = segs[lane * (nb16 + 1) + tix];
        else if (lane < 56) segv = segs[(lane - 28) * (nb16 + 1) + tix + 1];
        f32x4 d0 = {0.f, 0.f, 0.f, 0.f}, d1 = {0.f, 0.f, 0.f, 0.f};
        for (int k = 0; k < 27; ++k) {
            const int s0 = __shfl(segv, k);
            const int s1 = __shfl(segv, 28 + k);
            if (s0 == s1) continue;               // wave-uniform skip
            if (lane < 16) invw[wv * 16 + lane] = -1;
            const int e = s0 + lane;
            if (lane < 16 && e < s1)              // segment len <= 16 (unique routs)
                invw[wv * 16 + (rout[(size_t)k * P + e] - rowbase)] = rin[(size_t)k * P + e];
            asm volatile("s_waitcnt lgkmcnt(0)" ::: "memory");
            const int rn = invw[wv * 16 + row];
            unsigned au0 = 0, au1 = 0, au2 = 0, au3 = 0;
            if (rn >= 0) {
                const float4 v0 = *(const float4*)(feat + (size_t)rn * 32 + grp * 8);
                const float4 v1 = *(const float4*)(feat + (size_t)rn * 32 + grp * 8 + 4);
                au0 = f2bfu(v0.x) | (f2bfu(v0.y) << 16);
                au1 = f2bfu(v0.z) | (f2bfu(v0.w) << 16);
                au2 = f2bfu(v1.x) | (f2bfu(v1.y) << 16);
                au3 = f2bfu(v1.z) | (f2bfu(v1.w) << 16);
            }
            union { unsigned u[4]; bf16x8 v; } ua;
            ua.u[0] = au0; ua.u[1] = au1; ua.u[2] = au2; ua.u[3] = au3;
            const bf16x8 b0 = *(const bf16x8*)(Bp + ((size_t)(2 * k) * 64 + lane) * 8);
            const bf16x8 b1 = *(const bf16x8*)(Bp + ((size_t)(2 * k + 1) * 64 + lane) * 8);
            d0 = __builtin_amdgcn_mfma_f32_16x16x32_bf16(ua.v, b0, d0, 0, 0, 0);
            d1 = __builtin_amdgcn_mfma_f32_16x16x32_bf16(ua.v, b1, d1, 0, 0, 0);
        }
        const int m0 = rowbase + grp * 4;
#pragma unroll
        for (int i = 0; i < 4; i++) {
            if (m0 + i < n_out) {
                out[(size_t)(m0 + i) * 32 + row]      = d0[i];
                out[(size_t)(m0 + i) * 32 + row + 16] = d1[i];
            }
            ss0 += d0[i]; qq0 += d0[i] * d0[i];
            ss1 += d1[i]; qq1 += d1[i] * d1[i];
        }
    }
#pragma unroll
    for (int d = 16; d <= 32; d <<= 1) {
        ss0 += __shfl_xor(ss0, d); qq0 += __shfl_xor(qq0, d);
        ss1 += __shfl_xor(ss1, d); qq1 += __shfl_xor(qq1, d);
    }
    if (lane < 16) {
        part[0][wv][row] = ss0; part[0][wv][row + 16] = ss1;
        part[1][wv][row] = qq0; part[1][wv][row + 16] = qq1;
    }
    __syncthreads();
    if (t < 64) {
        const int which = t >> 5, co = t & 31;
        atomicAdd(&stats[which * 32 + co],
                  part[which][0][co] + part[which][1][co] +
                  part[which][2][co] + part[which][3][co]);
    }
}

// ---- MFMA gather conv, dense inverse map, CIN=16 (2 taps/step) COUT=32 ----
__global__ __launch_bounds__(256) void conv_mfma_inv16(
        const float* __restrict__ feat, const short* __restrict__ Bp,
        const int* __restrict__ inv, int n_out,
        float* __restrict__ out, float* __restrict__ stats) {
    __shared__ float part[2][4][32];
    const int t = threadIdx.x, wv = t >> 6, lane = t & 63;
    const int row = lane & 15, grp = lane >> 4;
    float ss0 = 0.f, qq0 = 0.f, ss1 = 0.f, qq1 = 0.f;

    for (int tile = 0; tile < 4; ++tile) {
        const int rowbase = blockIdx.x * 256 + wv * 64 + tile * 16;
        if (rowbase >= n_out) break;
        const int j = rowbase + row;
        f32x4 d0 = {0.f, 0.f, 0.f, 0.f}, d1 = {0.f, 0.f, 0.f, 0.f};
        for (int s = 0; s < 14; ++s) {
            const int tap = 2 * s + (grp >> 1);
            const int cin0 = (grp & 1) * 8;
            int rn = -1;
            if (tap < 27 && j < n_out) rn = inv[(size_t)tap * n_out + j];
            unsigned au0 = 0, au1 = 0, au2 = 0, au3 = 0;
            if (rn >= 0) {
                const float4 v0 = *(const float4*)(feat + (size_t)rn * 16 + cin0);
                const float4 v1 = *(const float4*)(feat + (size_t)rn * 16 + cin0 + 4);
                au0 = f2bfu(v0.x) | (f2bfu(v0.y) << 16);
                au1 = f2bfu(v0.z) | (f2bfu(v0.w) << 16);
                au2 = f2bfu(v1.x) | (f2bfu(v1.y) << 16);
                au3 = f2bfu(v1.z) | (f2bfu(v1.w) << 16);
            }
            union { unsigned u[4]; bf16x8 v; } ua;
            ua.u[0] = au0; ua.u[1] = au1; ua.u[2] = au2; ua.u[3] = au3;
            const bf16x8 b0 = *(const bf16x8*)(Bp + ((size_t)(2 * s) * 64 + lane) * 8);
            const bf16x8 b1 = *(const bf16x8*)(Bp + ((size_t)(2 * s + 1) * 64 + lane) * 8);
            d0 = __builtin_amdgcn_mfma_f32_16x16x32_bf16(ua.v, b0, d0, 0, 0, 0);
            d1 = __builtin_amdgcn_mfma_f32_16x16x32_bf16(ua.v, b1, d1, 0, 0, 0);
        }
        const int m0 = rowbase + grp * 4;
#pragma unroll
        for (int i = 0; i < 4; i++) {
            if (m0 + i < n_out) {
                out[(size_t)(m0 + i) * 32 + row]      = d0[i];
                out[(size_t)(m0 + i) * 32 + row + 16] = d1[i];
            }
            ss0 += d0[i]; qq0 += d0[i] * d0[i];
            ss1 += d1[i]; qq1 += d1[i] * d1[i];
        }
    }
#pragma unroll
    for (int d = 16; d <= 32; d <<= 1) {
        ss0 += __shfl_xor(ss0, d); qq0 += __shfl_xor(qq0, d);
        ss1 += __shfl_xor(ss1, d); qq1 += __shfl_xor(qq1, d);
    }
    if (lane < 16) {
        part[0][wv][row] = ss0; part[0][wv][row + 16] = ss1;
        part[1][wv][row] = qq0; part[1][wv][row + 16] = qq1;
    }
    __syncthreads();
    if (t < 64) {
        const int which = t >> 5, co = t & 31;
        atomicAdd(&stats[which * 32 + co],
                  part[which][0][co] + part[which][1][co] +
                  part[which][2][co] + part[which][3][co]);
    }
}

// ---- fp32 gather conv (stage 1: 16-ch chain + prune conv) -----------------
template <int CIN, int COUT, bool SIGMOID, bool STATS>
__global__ __launch_bounds__(256) void conv_gather(
        const float* __restrict__ feat, const float* __restrict__ W,
        const int* __restrict__ rin, const int* __restrict__ rout,
        const int* __restrict__ segs, int P, int n_out,
        float* __restrict__ out, float* __restrict__ stats) {
    __shared__ int2 invl[256];        // {tag k, rin}; valid iff tag == k
    __shared__ int seg[54];
    __shared__ float part[2][4][COUT];
    const int t = threadIdx.x;
    const int j0 = blockIdx.x * 256;
    const int nb1 = gridDim.x + 1;
    if (t < 54) seg[t] = segs[(t >> 1) * nb1 + blockIdx.x + (t & 1)];
    invl[t] = make_int2(-1, -1);
    float acc[COUT];
#pragma unroll
    for (int co = 0; co < COUT; co++) acc[co] = 0.f;
    __syncthreads();

    for (int k = 0; k < 27; k++) {
        const int s0 = seg[2 * k], s1 = seg[2 * k + 1];
        if (s0 == s1) continue;
        const int idx = s0 + t;
        if (idx < s1)
            invl[rout[(size_t)k * P + idx] - j0] = make_int2(k, rin[(size_t)k * P + idx]);
        __syncthreads();
        const int2 e = invl[t];
        const int in = (e.x == k) ? e.y : -1;
        __syncthreads();

        float f[CIN];
#pragma unroll
        for (int ci = 0; ci < CIN; ci++) f[ci] = 0.f;
        if (in >= 0) {
            const float* fr = feat + (size_t)in * CIN;
            if constexpr (CIN % 4 == 0) {
#pragma unroll
                for (int q = 0; q < CIN / 4; q++) {
                    const float4 v = *(const float4*)(fr + 4 * q);
                    f[4 * q] = v.x; f[4 * q + 1] = v.y;
                    f[4 * q + 2] = v.z; f[4 * q + 3] = v.w;
                }
            } else {
#pragma unroll
                for (int ci = 0; ci < CIN; ci++) f[ci] = fr[ci];
            }
        }
        const float* __restrict__ Wk = W + k * CIN * COUT;   // lane-uniform
#pragma unroll
        for (int ci = 0; ci < CIN; ci++) {
            const float fv = f[ci];
#pragma unroll
            for (int co = 0; co < COUT; co++)
                acc[co] = fmaf(fv, Wk[ci * COUT + co], acc[co]);
        }
    }

    const int j = j0 + t;
    if (j < n_out) {
#pragma unroll
        for (int co = 0; co < COUT; co++) {
            float v = acc[co];
            if (SIGMOID) v = 1.f / (1.f + expf(-v));
            out[(size_t)j * COUT + co] = v;
        }
    }
    if (STATS) {
        const int wv = t >> 6, lane = t & 63;
#pragma unroll
        for (int co = 0; co < COUT; co++) {
            float s = acc[co], s2 = s * s;
#pragma unroll
            for (int d = 1; d < 64; d <<= 1) {
                s += __shfl_xor(s, d);
                s2 += __shfl_xor(s2, d);
            }
            if (lane == 0) { part[0][wv][co] = s; part[1][wv][co] = s2; }
        }
        __syncthreads();
        if (t < 2 * COUT) {
            const int which = t / COUT, co = t - which * COUT;
            atomicAdd(&stats[which * COUT + co],
                      part[which][0][co] + part[which][1][co] +
                      part[which][2][co] + part[which][3][co]);
        }
    }
}

template <int C, bool RELU>
__global__ void bn_apply(const float* __restrict__ x, const float* __restrict__ stats,
                         const float* __restrict__ gg, const float* __restrict__ bb,
                         int n, float* __restrict__ y) {
    const float nf = (float)n;
    const long long total = (long long)n * C;
    for (long long idx = (long long)blockIdx.x * blockDim.x + threadIdx.x;
         idx < total; idx += (long long)gridDim.x * blockDim.x) {
        int ch = (int)(idx & (C - 1));
        float m = stats[ch] / nf;
        float v = stats[C + ch] / nf - m * m;
        float r = rsqrtf(v + 1e-3f);
        float val = gg[ch] * (x[idx] - m) * r + bb[ch];
        if (RELU) val = fmaxf(val, 0.f);
        y[idx] = val;
    }
}

template <int C>
__global__ void bn_apply_addrelu(const float* __restrict__ x,
                                 const float* __restrict__ skip,
                                 const float* __restrict__ stats,
                                 const float* __restrict__ gg,
                                 const float* __restrict__ bb,
                                 int n, float* __restrict__ y) {
    const float nf = (float)n;
    const long long total = (long long)n * C;
    for (long long idx = (long long)blockIdx.x * blockDim.x + threadIdx.x;
         idx < total; idx += (long long)gridDim.x * blockDim.x) {
        int ch = (int)(idx & (C - 1));
        float m = stats[ch] / nf;
        float v = stats[C + ch] / nf - m * m;
        float r = rsqrtf(v + 1e-3f);
        float val = gg[ch] * (x[idx] - m) * r + bb[ch] + skip[idx];
        y[idx] = fmaxf(val, 0.f);
    }
}

__global__ void hist_hi(const float* __restrict__ imp, int n, int* __restrict__ hist) {
    for (int i = blockIdx.x * blockDim.x + threadIdx.x; i < n;
         i += gridDim.x * blockDim.x) {
        unsigned b = __float_as_uint(imp[i]) >> 16;
        atomicAdd(&hist[b], 1);
    }
}

__global__ void hist_lo(const float* __restrict__ imp, int n,
                        const int* __restrict__ state, int* __restrict__ hist) {
    unsigned hb = (unsigned)state[0];
    for (int i = blockIdx.x * blockDim.x + threadIdx.x; i < n;
         i += gridDim.x * blockDim.x) {
        unsigned b = __float_as_uint(imp[i]);
        if ((b >> 16) == hb) atomicAdd(&hist[b & 0xffffu], 1);
    }
}

__global__ __launch_bounds__(256) void scan_sel(const int* __restrict__ hist,
                                                int kkeep, int phase,
                                                int* __restrict__ state) {
    __shared__ int csum[256];
    __shared__ int bins[256];
    __shared__ int sel_c, rem_c;
    const int t = threadIdx.x;
    const int target = (phase == 0) ? kkeep : state[1];
    int s = 0;
    const int* h = hist + t * 256;
    for (int i = 0; i < 256; i++) s += h[i];
    csum[t] = s;
    __syncthreads();
    if (t == 0) {
        int acc = 0; int c = 255;
        for (; c > 0; c--) {
            if (acc + csum[c] >= target) break;
            acc += csum[c];
        }
        sel_c = c; rem_c = target - acc;
    }
    __syncthreads();
    bins[t] = hist[sel_c * 256 + t];
    __syncthreads();
    if (t == 0) {
        int rem = rem_c;
        int acc = 0; int b = 255;
        for (; b > 0; b--) {
            if (acc + bins[b] >= rem) break;
            acc += bins[b];
        }
        int bucket = sel_c * 256 + b;
        if (phase == 0) { state[0] = bucket; state[1] = rem - acc; }
        else            { state[2] = (int)(((unsigned)state[0] << 16) | (unsigned)bucket); }
    }
}

__global__ void prune_mask(float* __restrict__ x, const float* __restrict__ imp,
                           const int* __restrict__ state, int n) {
    const unsigned K = (unsigned)state[2];
    int i = blockIdx.x * blockDim.x + threadIdx.x;
    if (i >= n) return;
    float im = imp[i];
    float mult = (__float_as_uint(im) >= K) ? im : 0.f;
#pragma unroll
    for (int c = 0; c < 16; c++) x[(size_t)i * 16 + c] *= mult;
}

extern "C" void kernel_launch(void* const* d_in, const int* in_sizes, int n_in,
                              void* d_out, int out_size, void* d_ws, size_t ws_size,
                              hipStream_t stream) {
    const float* vf    = (const float*)d_in[0];
    const float* W_in  = (const float*)d_in[1];
    const float* g_in  = (const float*)d_in[2];
    const float* b_in  = (const float*)d_in[3];
    const float* Wb1   = (const float*)d_in[4];
    const float* gb1   = (const float*)d_in[6];
    const float* beb1  = (const float*)d_in[7];
    const float* Wp    = (const float*)d_in[8];
    const float* Wd    = (const float*)d_in[9];
    const float* g_d   = (const float*)d_in[10];
    const float* b_d   = (const float*)d_in[11];
    const float* Wb2   = (const float*)d_in[12];
    const float* gb2   = (const float*)d_in[14];
    const float* beb2  = (const float*)d_in[15];
    const int* rb1_in  = (const int*)d_in[16];
    const int* rb1_out = (const int*)d_in[17];
    const int* rbd_in  = (const int*)d_in[18];
    const int* rbd_out = (const int*)d_in[19];
    const int* rb2_in  = (const int*)d_in[20];
    const int* rb2_out = (const int*)d_in[21];

    const int N  = in_sizes[0] / 5;
    const int P1 = in_sizes[16] / 27;
    const int Pd = in_sizes[18] / 27;
    const int P2 = in_sizes[20] / 27;
    const int n2 = out_size / 32;
    const int kkeep = N - N / 2;

    const int gs1   = (N + 255) / 256;        // 256-row blocks over N
    const int gm2   = (n2 + 255) / 256;       // 256-row MFMA blocks over n2
    const int nb16  = (n2 + 15) / 16;         // 16-row tiles over n2
    const int gew   = 2048;

    // workspace layout (floats); regions 16B-aligned
    auto pad4 = [](size_t v) { return (v + 3) & ~(size_t)3; };
    float* A     = (float*)d_ws;                       // N x 16
    float* B     = A   + pad4((size_t)N * 16);         // N x 16 (later: segs16)
    float* imp   = B   + pad4((size_t)N * 16);         // N     (later: W packs)
    float* D     = imp + pad4((size_t)N);              // n2 x 32 (stage-2 skip)
    float* E     = D   + pad4((size_t)n2 * 32);        // n2 x 32 (first: invd ints)
    float* stats = E   + pad4((size_t)n2 * 32);        // 64
    int*   cnt1  = (int*)(stats + 64);
    int*   cntd  = cnt1 + 32;
    int*   cnt2  = cntd + 32;
    int*   hist  = cnt2 + 32;                          // 65536
    int*   state = hist + 65536;                       // 8
    int*   segs1 = state + 8;                          // 27 * (gs1+1)
    int*   invd   = (int*)E;                           // 27 * n2 ints (<= E)
    int*   segs16 = (int*)B;                           // 27 * (nb16+1) ints (B dead)
    short* pack2  = (short*)imp;                       // 4 * 27648 shorts (imp dead)
    short* packd  = pack2 + 4 * 27648;                 // 14336 shorts
    float* OUT   = (float*)d_out;
    float* C2    = OUT;                                // stage-1 scratch (16N <= 32n2)

    rb_count_kernel<<<1, 32, 0, stream>>>(rb1_out, P1, N,  cnt1);
    rb_count_kernel<<<1, 32, 0, stream>>>(rbd_out, Pd, n2, cntd);
    rb_count_kernel<<<1, 32, 0, stream>>>(rb2_out, P2, n2, cnt2);
    seg_build<<<dim3((gs1 + 256) / 256, 27), 256, 0, stream>>>(rb1_out, cnt1, P1, gs1, 256, segs1);

    // ---- stage 1 (fp32): conv_input + BN + ReLU -> A
    hipMemsetAsync(stats, 0, 64 * 4, stream);
    conv_gather<5, 16, false, true><<<gs1, 256, 0, stream>>>(vf, W_in, rb1_in, rb1_out, segs1, P1, N, B, stats);
    bn_apply<16, true><<<gew, 256, 0, stream>>>(B, stats, g_in, b_in, N, A);

    for (int i = 0; i < 2; i++) {
        const float* W0 = Wb1 + (size_t)(i * 2 + 0) * 27 * 256;
        const float* W1 = Wb1 + (size_t)(i * 2 + 1) * 27 * 256;
        hipMemsetAsync(stats, 0, 64 * 4, stream);
        conv_gather<16, 16, false, true><<<gs1, 256, 0, stream>>>(A, W0, rb1_in, rb1_out, segs1, P1, N, B, stats);
        bn_apply<16, true><<<gew, 256, 0, stream>>>(B, stats, gb1 + (i * 2 + 0) * 16, beb1 + (i * 2 + 0) * 16, N, B);
        hipMemsetAsync(stats, 0, 64 * 4, stream);
        conv_gather<16, 16, false, true><<<gs1, 256, 0, stream>>>(B, W1, rb1_in, rb1_out, segs1, P1, N, C2, stats);
        bn_apply_addrelu<16><<<gew, 256, 0, stream>>>(C2, A, stats, gb1 + (i * 2 + 1) * 16, beb1 + (i * 2 + 1) * 16, N, A);
    }

    // ---- pruning (fp32-exact mask)
    conv_gather<16, 1, true, false><<<gs1, 256, 0, stream>>>(A, Wp, rb1_in, rb1_out, segs1, P1, N, imp, stats);
    hipMemsetAsync(hist, 0, 65536 * 4, stream);
    hist_hi<<<512, 256, 0, stream>>>(imp, N, hist);
    scan_sel<<<1, 256, 0, stream>>>(hist, kkeep, 0, state);
    hipMemsetAsync(hist, 0, 65536 * 4, stream);
    hist_lo<<<512, 256, 0, stream>>>(imp, N, state, hist);
    scan_sel<<<1, 256, 0, stream>>>(hist, kkeep, 1, state);
    prune_mask<<<(N + 255) / 256, 256, 0, stream>>>(A, imp, state, N);

    // ---- stage-2 setup (B and imp regions are dead now)
    seg_build<<<dim3((nb16 + 256) / 256, 27), 256, 0, stream>>>(rb2_out, cnt2, P2, nb16, 16, segs16);
    for (int w = 0; w < 4; w++)
        prepack_w<<<14, 256, 0, stream>>>(Wb2 + (size_t)w * 27 * 1024, 27, 32, 27, pack2 + (size_t)w * 27648);
    prepack_w<<<7, 256, 0, stream>>>(Wd, 27, 16, 14, packd);
    hipMemsetAsync(invd, 0xFF, (size_t)27 * n2 * 4, stream);
    inv_build<<<dim3((Pd + 255) / 256, 27), 256, 0, stream>>>(rbd_in, rbd_out, cntd, Pd, n2, invd);

    // ---- strided downsample 16->32 (MFMA) + BN + ReLU -> D
    hipMemsetAsync(stats, 0, 64 * 4, stream);
    conv_mfma_inv16<<<gm2, 256, 0, stream>>>(A, packd, invd, n2, D, stats);
    bn_apply<32, true><<<gew, 256, 0, stream>>>(D, stats, g_d, b_d, n2, D);

    // ---- conv2: 2x SparseBasicBlock @32 (MFMA)
    for (int i = 0; i < 2; i++) {
        const short* P0 = pack2 + (size_t)(i * 2 + 0) * 27648;
        const short* P1w = pack2 + (size_t)(i * 2 + 1) * 27648;
        hipMemsetAsync(stats, 0, 64 * 4, stream);
        conv_mfma_sorted32<<<gm2, 256, 0, stream>>>(D, P0, rb2_in, rb2_out, segs16, P2, nb16, n2, E, stats);
        bn_apply<32, true><<<gew, 256, 0, stream>>>(E, stats, gb2 + (i * 2 + 0) * 32, beb2 + (i * 2 + 0) * 32, n2, E);
        hipMemsetAsync(stats, 0, 64 * 4, stream);
        conv_mfma_sorted32<<<gm2, 256, 0, stream>>>(E, P1w, rb2_in, rb2_out, segs16, P2, nb16, n2, OUT, stats);
        bn_apply_addrelu<32><<<gew, 256, 0, stream>>>(OUT, D, stats, gb2 + (i * 2 + 1) * 32, beb2 + (i * 2 + 1) * 32, n2, (i == 0) ? D : OUT);
    }
}

// Round 6
// 1522.469 us; speedup vs baseline: 32.4457x; 1.2649x over previous
//
#include <hip/hip_runtime.h>

// ---------------------------------------------------------------------------
// Sparse 3D conv backbone.
// Stage 1 (fp32, bit-exact mask): conv_input 5->16 + BN + ReLU, 2x BasicBlock
//   @16 (rb1, barrier-free wave-tile gather), prune conv 16->1 + sigmoid,
//   exact top-k via 4-pass byte radix (LDS-privatized histograms).
// Stage 2 (bf16 MFMA): strided conv 16->32 (dense inverse map), 2x BasicBlock
//   @32 (rb2, wave-tile MFMA gather). BN-stats fused everywhere.
// ---------------------------------------------------------------------------

typedef __attribute__((ext_vector_type(8))) short bf16x8;
typedef __attribute__((ext_vector_type(4))) float f32x4;

static __device__ __forceinline__ unsigned f2bfu(float x) {   // fp32->bf16 RNE
    unsigned b = __float_as_uint(x);
    return (b + 0x7FFFu + ((b >> 16) & 1u)) >> 16;
}

__global__ void rb_count_kernel(const int* __restrict__ rout, int P, int n_out,
                                int* __restrict__ cnt) {
    int k = threadIdx.x;
    if (k >= 27) return;
    const int* r = rout + (size_t)k * P;
    int lo = 0, hi = P;
    while (lo < hi) {
        int mid = (lo + hi) >> 1;
        if (r[mid] < n_out) lo = mid + 1; else hi = mid;
    }
    cnt[k] = lo;
}

// segs[k][b] = lower_bound(rout[k], b*gran), b in [0, nb]
__global__ void seg_build(const int* __restrict__ rout, const int* __restrict__ cnt,
                          int P, int nb, int gran, int* __restrict__ segs) {
    const int k = blockIdx.y;
    const int b = blockIdx.x * 256 + threadIdx.x;
    if (b > nb) return;
    const int target = b * gran;
    const int* r = rout + (size_t)k * P;
    int lo = 0, hi = cnt[k];
    while (lo < hi) {
        int m = (lo + hi) >> 1;
        if (r[m] < target) lo = m + 1; else hi = m;
    }
    segs[k * (nb + 1) + b] = lo;
}

__global__ void inv_build(const int* __restrict__ rin, const int* __restrict__ rout,
                          const int* __restrict__ cnt, int P, int n_out,
                          int* __restrict__ inv) {
    const int k = blockIdx.y;
    const int p = blockIdx.x * 256 + threadIdx.x;
    if (p < cnt[k])
        inv[(size_t)k * n_out + rout[(size_t)k * P + p]] = rin[(size_t)k * P + p];
}

// Pre-pack fp32 weights [T][CI][32] into MFMA B-frag bf16 order.
__global__ void prepack_w(const float* __restrict__ W, int T, int CI, int S,
                          short* __restrict__ pack) {
    int idx = blockIdx.x * 256 + threadIdx.x;     // over S*128
    if (idx >= S * 128) return;
    int l = idx & 63, h = (idx >> 6) & 1, s = idx >> 7;
    int co = (l & 15) + 16 * h;
#pragma unroll
    for (int j = 0; j < 8; j++) {
        int gk = s * 32 + (l >> 4) * 8 + j;
        int tap = gk / CI, cin = gk % CI;
        float w = (tap < T) ? W[((size_t)tap * CI + cin) * 32 + co] : 0.f;
        pack[(size_t)idx * 8 + j] = (short)f2bfu(w);
    }
}

// ---- MFMA gather conv, sorted rulebook, CIN=32 COUT=32 (rb2) --------------
__global__ __launch_bounds__(256) void conv_mfma_sorted32(
        const float* __restrict__ feat, const short* __restrict__ Bp,
        const int* __restrict__ rin, const int* __restrict__ rout,
        const int* __restrict__ segs, int P, int nb16, int n_out,
        float* __restrict__ out, float* __restrict__ stats) {
    __shared__ int invw[64];
    __shared__ float part[2][4][32];
    const int t = threadIdx.x, wv = t >> 6, lane = t & 63;
    const int row = lane & 15, grp = lane >> 4;
    float ss0 = 0.f, qq0 = 0.f, ss1 = 0.f, qq1 = 0.f;

    for (int tile = 0; tile < 4; ++tile) {
        const int rowbase = blockIdx.x * 256 + wv * 64 + tile * 16;
        if (rowbase >= n_out) break;
        const int tix = rowbase >> 4;
        int segv = 0;
        if (lane < 28)      segv = segs[lane * (nb16 + 1) + tix];
        else if (lane < 56) segv = segs[(lane - 28) * (nb16 + 1) + tix + 1];
        f32x4 d0 = {0.f, 0.f, 0.f, 0.f}, d1 = {0.f, 0.f, 0.f, 0.f};
        for (int k = 0; k < 27; ++k) {
            const int s0 = __shfl(segv, k);
            const int s1 = __shfl(segv, 28 + k);
            if (s0 == s1) continue;               // wave-uniform skip
            if (lane < 16) invw[wv * 16 + lane] = -1;
            const int e = s0 + lane;
            if (lane < 16 && e < s1)              // segment len <= 16
                invw[wv * 16 + (rout[(size_t)k * P + e] - rowbase)] = rin[(size_t)k * P + e];
            asm volatile("s_waitcnt lgkmcnt(0)" ::: "memory");
            const int rn = invw[wv * 16 + row];
            unsigned au0 = 0, au1 = 0, au2 = 0, au3 = 0;
            if (rn >= 0) {
                const float4 v0 = *(const float4*)(feat + (size_t)rn * 32 + grp * 8);
                const float4 v1 = *(const float4*)(feat + (size_t)rn * 32 + grp * 8 + 4);
                au0 = f2bfu(v0.x) | (f2bfu(v0.y) << 16);
                au1 = f2bfu(v0.z) | (f2bfu(v0.w) << 16);
                au2 = f2bfu(v1.x) | (f2bfu(v1.y) << 16);
                au3 = f2bfu(v1.z) | (f2bfu(v1.w) << 16);
            }
            union { unsigned u[4]; bf16x8 v; } ua;
            ua.u[0] = au0; ua.u[1] = au1; ua.u[2] = au2; ua.u[3] = au3;
            const bf16x8 b0 = *(const bf16x8*)(Bp + ((size_t)(2 * k) * 64 + lane) * 8);
            const bf16x8 b1 = *(const bf16x8*)(Bp + ((size_t)(2 * k + 1) * 64 + lane) * 8);
            d0 = __builtin_amdgcn_mfma_f32_16x16x32_bf16(ua.v, b0, d0, 0, 0, 0);
            d1 = __builtin_amdgcn_mfma_f32_16x16x32_bf16(ua.v, b1, d1, 0, 0, 0);
        }
        const int m0 = rowbase + grp * 4;
#pragma unroll
        for (int i = 0; i < 4; i++) {
            if (m0 + i < n_out) {
                out[(size_t)(m0 + i) * 32 + row]      = d0[i];
                out[(size_t)(m0 + i) * 32 + row + 16] = d1[i];
            }
            ss0 += d0[i]; qq0 += d0[i] * d0[i];
            ss1 += d1[i]; qq1 += d1[i] * d1[i];
        }
    }
#pragma unroll
    for (int d = 16; d <= 32; d <<= 1) {
        ss0 += __shfl_xor(ss0, d); qq0 += __shfl_xor(qq0, d);
        ss1 += __shfl_xor(ss1, d); qq1 += __shfl_xor(qq1, d);
    }
    if (lane < 16) {
        part[0][wv][row] = ss0; part[0][wv][row + 16] = ss1;
        part[1][wv][row] = qq0; part[1][wv][row + 16] = qq1;
    }
    __syncthreads();
    if (t < 64) {
        const int which = t >> 5, co = t & 31;
        atomicAdd(&stats[which * 32 + co],
                  part[which][0][co] + part[which][1][co] +
                  part[which][2][co] + part[which][3][co]);
    }
}

// ---- MFMA gather conv, dense inverse map, CIN=16 (2 taps/step) COUT=32 ----
__global__ __launch_bounds__(256) void conv_mfma_inv16(
        const float* __restrict__ feat, const short* __restrict__ Bp,
        const int* __restrict__ inv, int n_out,
        float* __restrict__ out, float* __restrict__ stats) {
    __shared__ float part[2][4][32];
    const int t = threadIdx.x, wv = t >> 6, lane = t & 63;
    const int row = lane & 15, grp = lane >> 4;
    float ss0 = 0.f, qq0 = 0.f, ss1 = 0.f, qq1 = 0.f;

    for (int tile = 0; tile < 4; ++tile) {
        const int rowbase = blockIdx.x * 256 + wv * 64 + tile * 16;
        if (rowbase >= n_out) break;
        const int j = rowbase + row;
        f32x4 d0 = {0.f, 0.f, 0.f, 0.f}, d1 = {0.f, 0.f, 0.f, 0.f};
        for (int s = 0; s < 14; ++s) {
            const int tap = 2 * s + (grp >> 1);
            const int cin0 = (grp & 1) * 8;
            int rn = -1;
            if (tap < 27 && j < n_out) rn = inv[(size_t)tap * n_out + j];
            unsigned au0 = 0, au1 = 0, au2 = 0, au3 = 0;
            if (rn >= 0) {
                const float4 v0 = *(const float4*)(feat + (size_t)rn * 16 + cin0);
                const float4 v1 = *(const float4*)(feat + (size_t)rn * 16 + cin0 + 4);
                au0 = f2bfu(v0.x) | (f2bfu(v0.y) << 16);
                au1 = f2bfu(v0.z) | (f2bfu(v0.w) << 16);
                au2 = f2bfu(v1.x) | (f2bfu(v1.y) << 16);
                au3 = f2bfu(v1.z) | (f2bfu(v1.w) << 16);
            }
            union { unsigned u[4]; bf16x8 v; } ua;
            ua.u[0] = au0; ua.u[1] = au1; ua.u[2] = au2; ua.u[3] = au3;
            const bf16x8 b0 = *(const bf16x8*)(Bp + ((size_t)(2 * s) * 64 + lane) * 8);
            const bf16x8 b1 = *(const bf16x8*)(Bp + ((size_t)(2 * s + 1) * 64 + lane) * 8);
            d0 = __builtin_amdgcn_mfma_f32_16x16x32_bf16(ua.v, b0, d0, 0, 0, 0);
            d1 = __builtin_amdgcn_mfma_f32_16x16x32_bf16(ua.v, b1, d1, 0, 0, 0);
        }
        const int m0 = rowbase + grp * 4;
#pragma unroll
        for (int i = 0; i < 4; i++) {
            if (m0 + i < n_out) {
                out[(size_t)(m0 + i) * 32 + row]      = d0[i];
                out[(size_t)(m0 + i) * 32 + row + 16] = d1[i];
            }
            ss0 += d0[i]; qq0 += d0[i] * d0[i];
            ss1 += d1[i]; qq1 += d1[i] * d1[i];
        }
    }
#pragma unroll
    for (int d = 16; d <= 32; d <<= 1) {
        ss0 += __shfl_xor(ss0, d); qq0 += __shfl_xor(qq0, d);
        ss1 += __shfl_xor(ss1, d); qq1 += __shfl_xor(qq1, d);
    }
    if (lane < 16) {
        part[0][wv][row] = ss0; part[0][wv][row + 16] = ss1;
        part[1][wv][row] = qq0; part[1][wv][row + 16] = qq1;
    }
    __syncthreads();
    if (t < 64) {
        const int which = t >> 5, co = t & 31;
        atomicAdd(&stats[which * 32 + co],
                  part[which][0][co] + part[which][1][co] +
                  part[which][2][co] + part[which][3][co]);
    }
}

// ---- fp32 wave-tile gather conv, CIN=16 (rb1: 16ch chain + prune conv) ----
// One wave owns 64 output rows; per-tap inverse map in per-wave LDS slice,
// wave-synchronous (lgkmcnt), no block barriers in the k-loop.
template <int COUT, bool SIGMOID, bool STATS>
__global__ __launch_bounds__(256) void conv16_wave(
        const float* __restrict__ feat, const float* __restrict__ W,
        const int* __restrict__ rin, const int* __restrict__ rout,
        const int* __restrict__ segs, int P, int nb64, int n_out,
        float* __restrict__ out, float* __restrict__ stats) {
    __shared__ int invw[4 * 64];
    __shared__ float part[2][4][COUT];
    const int t = threadIdx.x, wv = t >> 6, lane = t & 63;
    const int rowbase = blockIdx.x * 256 + wv * 64;
    const bool active = rowbase < n_out;
    float acc[COUT];
#pragma unroll
    for (int co = 0; co < COUT; co++) acc[co] = 0.f;

    if (active) {
        const int tix = rowbase >> 6;
        int segv = 0;
        if (lane < 28)      segv = segs[lane * (nb64 + 1) + tix];
        else if (lane < 56) segv = segs[(lane - 28) * (nb64 + 1) + tix + 1];
        for (int k = 0; k < 27; ++k) {
            const int s0 = __shfl(segv, k);
            const int s1 = __shfl(segv, 28 + k);
            if (s0 == s1) continue;               // wave-uniform skip
            invw[wv * 64 + lane] = -1;
            const int e = s0 + lane;              // segment len <= 64
            if (e < s1)
                invw[wv * 64 + (rout[(size_t)k * P + e] - rowbase)] = rin[(size_t)k * P + e];
            asm volatile("s_waitcnt lgkmcnt(0)" ::: "memory");
            const int rn = invw[wv * 64 + lane];
            float f[16];
#pragma unroll
            for (int ci = 0; ci < 16; ci++) f[ci] = 0.f;
            if (rn >= 0) {
                const float* fr = feat + (size_t)rn * 16;
#pragma unroll
                for (int q = 0; q < 4; q++) {
                    const float4 v = *(const float4*)(fr + 4 * q);
                    f[4 * q] = v.x; f[4 * q + 1] = v.y;
                    f[4 * q + 2] = v.z; f[4 * q + 3] = v.w;
                }
            }
            const float* __restrict__ Wk = W + k * 16 * COUT;   // lane-uniform
#pragma unroll
            for (int ci = 0; ci < 16; ci++) {
                const float fv = f[ci];
#pragma unroll
                for (int co = 0; co < COUT; co++)
                    acc[co] = fmaf(fv, Wk[ci * COUT + co], acc[co]);
            }
        }
        const int j = rowbase + lane;
        if (j < n_out) {
#pragma unroll
            for (int co = 0; co < COUT; co++) {
                float v = acc[co];
                if (SIGMOID) v = 1.f / (1.f + expf(-v));
                out[(size_t)j * COUT + co] = v;
            }
        }
    }
    if (STATS) {
#pragma unroll
        for (int co = 0; co < COUT; co++) {
            float s = acc[co], s2 = s * s;
#pragma unroll
            for (int d = 1; d < 64; d <<= 1) {
                s += __shfl_xor(s, d);
                s2 += __shfl_xor(s2, d);
            }
            if (lane == 0) { part[0][wv][co] = s; part[1][wv][co] = s2; }
        }
        __syncthreads();
        if (t < 2 * COUT) {
            const int which = t / COUT, co = t - which * COUT;
            atomicAdd(&stats[which * COUT + co],
                      part[which][0][co] + part[which][1][co] +
                      part[which][2][co] + part[which][3][co]);
        }
    }
}

// ---- fp32 block gather conv (conv_input 5->16 only) -----------------------
template <int CIN, int COUT>
__global__ __launch_bounds__(256) void conv_gather(
        const float* __restrict__ feat, const float* __restrict__ W,
        const int* __restrict__ rin, const int* __restrict__ rout,
        const int* __restrict__ segs, int P, int n_out,
        float* __restrict__ out, float* __restrict__ stats) {
    __shared__ int2 invl[256];        // {tag k, rin}; valid iff tag == k
    __shared__ int seg[54];
    __shared__ float part[2][4][COUT];
    const int t = threadIdx.x;
    const int j0 = blockIdx.x * 256;
    const int nb1 = gridDim.x + 1;
    if (t < 54) seg[t] = segs[(t >> 1) * nb1 + blockIdx.x + (t & 1)];
    invl[t] = make_int2(-1, -1);
    float acc[COUT];
#pragma unroll
    for (int co = 0; co < COUT; co++) acc[co] = 0.f;
    __syncthreads();

    for (int k = 0; k < 27; k++) {
        const int s0 = seg[2 * k], s1 = seg[2 * k + 1];
        if (s0 == s1) continue;
        const int idx = s0 + t;
        if (idx < s1)
            invl[rout[(size_t)k * P + idx] - j0] = make_int2(k, rin[(size_t)k * P + idx]);
        __syncthreads();
        const int2 e = invl[t];
        const int in = (e.x == k) ? e.y : -1;
        __syncthreads();

        float f[CIN];
#pragma unroll
        for (int ci = 0; ci < CIN; ci++) f[ci] = 0.f;
        if (in >= 0) {
            const float* fr = feat + (size_t)in * CIN;
#pragma unroll
            for (int ci = 0; ci < CIN; ci++) f[ci] = fr[ci];
        }
        const float* __restrict__ Wk = W + k * CIN * COUT;   // lane-uniform
#pragma unroll
        for (int ci = 0; ci < CIN; ci++) {
            const float fv = f[ci];
#pragma unroll
            for (int co = 0; co < COUT; co++)
                acc[co] = fmaf(fv, Wk[ci * COUT + co], acc[co]);
        }
    }

    const int j = j0 + t;
    if (j < n_out) {
#pragma unroll
        for (int co = 0; co < COUT; co++) out[(size_t)j * COUT + co] = acc[co];
    }
    const int wv = t >> 6, lane = t & 63;
#pragma unroll
    for (int co = 0; co < COUT; co++) {
        float s = acc[co], s2 = s * s;
#pragma unroll
        for (int d = 1; d < 64; d <<= 1) {
            s += __shfl_xor(s, d);
            s2 += __shfl_xor(s2, d);
        }
        if (lane == 0) { part[0][wv][co] = s; part[1][wv][co] = s2; }
    }
    __syncthreads();
    if (t < 2 * COUT) {
        const int which = t / COUT, co = t - which * COUT;
        atomicAdd(&stats[which * COUT + co],
                  part[which][0][co] + part[which][1][co] +
                  part[which][2][co] + part[which][3][co]);
    }
}

template <int C, bool RELU>
__global__ void bn_apply(const float* __restrict__ x, const float* __restrict__ stats,
                         const float* __restrict__ gg, const float* __restrict__ bb,
                         int n, float* __restrict__ y) {
    const float nf = (float)n;
    const long long total = (long long)n * C;
    for (long long idx = (long long)blockIdx.x * blockDim.x + threadIdx.x;
         idx < total; idx += (long long)gridDim.x * blockDim.x) {
        int ch = (int)(idx & (C - 1));
        float m = stats[ch] / nf;
        float v = stats[C + ch] / nf - m * m;
        float r = rsqrtf(v + 1e-3f);
        float val = gg[ch] * (x[idx] - m) * r + bb[ch];
        if (RELU) val = fmaxf(val, 0.f);
        y[idx] = val;
    }
}

template <int C>
__global__ void bn_apply_addrelu(const float* __restrict__ x,
                                 const float* __restrict__ skip,
                                 const float* __restrict__ stats,
                                 const float* __restrict__ gg,
                                 const float* __restrict__ bb,
                                 int n, float* __restrict__ y) {
    const float nf = (float)n;
    const long long total = (long long)n * C;
    for (long long idx = (long long)blockIdx.x * blockDim.x + threadIdx.x;
         idx < total; idx += (long long)gridDim.x * blockDim.x) {
        int ch = (int)(idx & (C - 1));
        float m = stats[ch] / nf;
        float v = stats[C + ch] / nf - m * m;
        float r = rsqrtf(v + 1e-3f);
        float val = gg[ch] * (x[idx] - m) * r + bb[ch] + skip[idx];
        y[idx] = fmaxf(val, 0.f);
    }
}

// ---- exact top-k: 4-pass byte radix, LDS-privatized histograms ------------
__global__ __launch_bounds__(256) void hist_pass(const float* __restrict__ imp, int n,
                                                 int pass, const int* __restrict__ state,
                                                 int* __restrict__ hist) {
    __shared__ int lh[256];
    const int t = threadIdx.x;
    lh[t] = 0;
    __syncthreads();
    const int shift = 24 - 8 * pass;
    unsigned prefix = 0;
    if (pass > 0) prefix = (unsigned)state[0];
    for (int i = blockIdx.x * 256 + t; i < n; i += gridDim.x * 256) {
        unsigned u = __float_as_uint(imp[i]);
        if (pass == 0 || (u >> (shift + 8)) == prefix)
            atomicAdd(&lh[(u >> shift) & 0xFFu], 1);
    }
    __syncthreads();
    if (lh[t]) atomicAdd(&hist[pass * 256 + t], lh[t]);
}

__global__ __launch_bounds__(256) void scan_byte(const int* __restrict__ hist,
                                                 int kkeep, int pass,
                                                 int* __restrict__ state) {
    __shared__ int h[256];
    const int t = threadIdx.x;
    h[t] = hist[pass * 256 + t];
    __syncthreads();
    if (t == 0) {
        const int target = (pass == 0) ? kkeep : state[1];
        int acc = 0; int b = 255;
        for (; b > 0; b--) {
            if (acc + h[b] >= target) break;
            acc += h[b];
        }
        unsigned prefix = (pass == 0) ? 0u : (unsigned)state[0];
        prefix = (prefix << 8) | (unsigned)b;
        state[0] = (int)prefix;
        state[1] = target - acc;
        if (pass == 3) state[2] = (int)prefix;   // exact bits of kth largest
    }
}

__global__ void prune_mask(float* __restrict__ x, const float* __restrict__ imp,
                           const int* __restrict__ state, int n) {
    const unsigned K = (unsigned)state[2];
    int i = blockIdx.x * blockDim.x + threadIdx.x;
    if (i >= n) return;
    float im = imp[i];
    float mult = (__float_as_uint(im) >= K) ? im : 0.f;
#pragma unroll
    for (int c = 0; c < 16; c++) x[(size_t)i * 16 + c] *= mult;
}

extern "C" void kernel_launch(void* const* d_in, const int* in_sizes, int n_in,
                              void* d_out, int out_size, void* d_ws, size_t ws_size,
                              hipStream_t stream) {
    const float* vf    = (const float*)d_in[0];
    const float* W_in  = (const float*)d_in[1];
    const float* g_in  = (const float*)d_in[2];
    const float* b_in  = (const float*)d_in[3];
    const float* Wb1   = (const float*)d_in[4];
    const float* gb1   = (const float*)d_in[6];
    const float* beb1  = (const float*)d_in[7];
    const float* Wp    = (const float*)d_in[8];
    const float* Wd    = (const float*)d_in[9];
    const float* g_d   = (const float*)d_in[10];
    const float* b_d   = (const float*)d_in[11];
    const float* Wb2   = (const float*)d_in[12];
    const float* gb2   = (const float*)d_in[14];
    const float* beb2  = (const float*)d_in[15];
    const int* rb1_in  = (const int*)d_in[16];
    const int* rb1_out = (const int*)d_in[17];
    const int* rbd_in  = (const int*)d_in[18];
    const int* rbd_out = (const int*)d_in[19];
    const int* rb2_in  = (const int*)d_in[20];
    const int* rb2_out = (const int*)d_in[21];

    const int N  = in_sizes[0] / 5;
    const int P1 = in_sizes[16] / 27;
    const int Pd = in_sizes[18] / 27;
    const int P2 = in_sizes[20] / 27;
    const int n2 = out_size / 32;
    const int kkeep = N - N / 2;

    const int gs1   = (N + 255) / 256;        // 256-row blocks over N
    const int gm2   = (n2 + 255) / 256;       // 256-row MFMA blocks over n2
    const int nb16  = (n2 + 15) / 16;         // 16-row tiles over n2
    const int nb64  = (N + 63) / 64;          // 64-row tiles over N
    const int gew   = 2048;

    // workspace layout (floats); regions 16B-aligned
    auto pad4 = [](size_t v) { return (v + 3) & ~(size_t)3; };
    float* A     = (float*)d_ws;                       // N x 16
    float* B     = A   + pad4((size_t)N * 16);         // N x 16 (later: segs16)
    float* imp   = B   + pad4((size_t)N * 16);         // N     (later: W packs)
    float* D     = imp + pad4((size_t)N);              // n2 x 32 (stage-2 skip)
    float* E     = D   + pad4((size_t)n2 * 32);        // n2 x 32 (first: invd ints)
    float* stats = E   + pad4((size_t)n2 * 32);        // 64
    int*   cnt1  = (int*)(stats + 64);
    int*   cntd  = cnt1 + 32;
    int*   cnt2  = cntd + 32;
    int*   hist4 = cnt2 + 32;                          // 4 * 256
    int*   state = hist4 + 1024;                       // 8
    int*   segs1 = state + 8;                          // 27 * (gs1+1)
    int*   segs64 = segs1 + 27 * (gs1 + 1);            // 27 * (nb64+1)
    int*   invd   = (int*)E;                           // 27 * n2 ints (<= E)
    int*   segs16 = (int*)B;                           // 27 * (nb16+1) (B dead)
    short* pack2  = (short*)imp;                       // 4 * 27648 shorts (imp dead)
    short* packd  = pack2 + 4 * 27648;                 // 14336 shorts
    float* OUT   = (float*)d_out;
    float* C2    = OUT;                                // stage-1 scratch (16N <= 32n2)

    rb_count_kernel<<<1, 32, 0, stream>>>(rb1_out, P1, N,  cnt1);
    rb_count_kernel<<<1, 32, 0, stream>>>(rbd_out, Pd, n2, cntd);
    rb_count_kernel<<<1, 32, 0, stream>>>(rb2_out, P2, n2, cnt2);
    seg_build<<<dim3((gs1 + 256) / 256, 27), 256, 0, stream>>>(rb1_out, cnt1, P1, gs1, 256, segs1);
    seg_build<<<dim3((nb64 + 256) / 256, 27), 256, 0, stream>>>(rb1_out, cnt1, P1, nb64, 64, segs64);

    // ---- stage 1 (fp32): conv_input + BN + ReLU -> A
    hipMemsetAsync(stats, 0, 64 * 4, stream);
    conv_gather<5, 16><<<gs1, 256, 0, stream>>>(vf, W_in, rb1_in, rb1_out, segs1, P1, N, B, stats);
    bn_apply<16, true><<<gew, 256, 0, stream>>>(B, stats, g_in, b_in, N, A);

    for (int i = 0; i < 2; i++) {
        const float* W0 = Wb1 + (size_t)(i * 2 + 0) * 27 * 256;
        const float* W1 = Wb1 + (size_t)(i * 2 + 1) * 27 * 256;
        hipMemsetAsync(stats, 0, 64 * 4, stream);
        conv16_wave<16, false, true><<<gs1, 256, 0, stream>>>(A, W0, rb1_in, rb1_out, segs64, P1, nb64, N, B, stats);
        bn_apply<16, true><<<gew, 256, 0, stream>>>(B, stats, gb1 + (i * 2 + 0) * 16, beb1 + (i * 2 + 0) * 16, N, B);
        hipMemsetAsync(stats, 0, 64 * 4, stream);
        conv16_wave<16, false, true><<<gs1, 256, 0, stream>>>(B, W1, rb1_in, rb1_out, segs64, P1, nb64, N, C2, stats);
        bn_apply_addrelu<16><<<gew, 256, 0, stream>>>(C2, A, stats, gb1 + (i * 2 + 1) * 16, beb1 + (i * 2 + 1) * 16, N, A);
    }

    // ---- pruning: imp = sigmoid(conv 16->1); exact top-k via byte radix
    conv16_wave<1, true, false><<<gs1, 256, 0, stream>>>(A, Wp, rb1_in, rb1_out, segs64, P1, nb64, N, imp, stats);
    hipMemsetAsync(hist4, 0, 1024 * 4, stream);
    for (int p = 0; p < 4; p++) {
        hist_pass<<<128, 256, 0, stream>>>(imp, N, p, state, hist4);
        scan_byte<<<1, 256, 0, stream>>>(hist4, kkeep, p, state);
    }
    prune_mask<<<(N + 255) / 256, 256, 0, stream>>>(A, imp, state, N);

    // ---- stage-2 setup (B and imp regions are dead now)
    seg_build<<<dim3((nb16 + 256) / 256, 27), 256, 0, stream>>>(rb2_out, cnt2, P2, nb16, 16, segs16);
    for (int w = 0; w < 4; w++)
        prepack_w<<<14, 256, 0, stream>>>(Wb2 + (size_t)w * 27 * 1024, 27, 32, 27, pack2 + (size_t)w * 27648);
    prepack_w<<<7, 256, 0, stream>>>(Wd, 27, 16, 14, packd);
    hipMemsetAsync(invd, 0xFF, (size_t)27 * n2 * 4, stream);
    inv_build<<<dim3((Pd + 255) / 256, 27), 256, 0, stream>>>(rbd_in, rbd_out, cntd, Pd, n2, invd);

    // ---- strided downsample 16->32 (MFMA) + BN + ReLU -> D
    hipMemsetAsync(stats, 0, 64 * 4, stream);
    conv_mfma_inv16<<<gm2, 256, 0, stream>>>(A, packd, invd, n2, D, stats);
    bn_apply<32, true><<<gew, 256, 0, stream>>>(D, stats, g_d, b_d, n2, D);

    // ---- conv2: 2x SparseBasicBlock @32 (MFMA)
    for (int i = 0; i < 2; i++) {
        const short* P0 = pack2 + (size_t)(i * 2 + 0) * 27648;
        const short* P1w = pack2 + (size_t)(i * 2 + 1) * 27648;
        hipMemsetAsync(stats, 0, 64 * 4, stream);
        conv_mfma_sorted32<<<gm2, 256, 0, stream>>>(D, P0, rb2_in, rb2_out, segs16, P2, nb16, n2, E, stats);
        bn_apply<32, true><<<gew, 256, 0, stream>>>(E, stats, gb2 + (i * 2 + 0) * 32, beb2 + (i * 2 + 0) * 32, n2, E);
        hipMemsetAsync(stats, 0, 64 * 4, stream);
        conv_mfma_sorted32<<<gm2, 256, 0, stream>>>(E, P1w, rb2_in, rb2_out, segs16, P2, nb16, n2, OUT, stats);
        bn_apply_addrelu<32><<<gew, 256, 0, stream>>>(OUT, D, stats, gb2 + (i * 2 + 1) * 32, beb2 + (i * 2 + 1) * 32, n2, (i == 0) ? D : OUT);
    }
}

// Round 7
// 1282.289 us; speedup vs baseline: 38.5229x; 1.1873x over previous
//
#include <hip/hip_runtime.h>

// ---------------------------------------------------------------------------
// Sparse 3D conv backbone.
// Stage 1 (fp32, bit-exact mask): conv_input 5->16 + BN + ReLU, 2x BasicBlock
//   @16 (rb1, wave-tile gather), prune conv 16->1 + sigmoid, exact top-k via
//   4-pass byte radix.
// Stage 2 (bf16 MFMA, bf16 feature buffers): strided conv 16->32 (dense
//   inverse map), 2x BasicBlock @32 (rb2). BN fused stats + bf16 outputs.
// All gather convs use XCD-aware bijective block swizzle (L2 locality).
// ---------------------------------------------------------------------------

typedef __attribute__((ext_vector_type(8))) short bf16x8;
typedef __attribute__((ext_vector_type(4))) float f32x4;

static __device__ __forceinline__ unsigned f2bfu(float x) {   // fp32->bf16 RNE
    unsigned b = __float_as_uint(x);
    return (b + 0x7FFFu + ((b >> 16) & 1u)) >> 16;
}
static __device__ __forceinline__ float bf2f(unsigned short u) {
    return __uint_as_float(((unsigned)u) << 16);
}
// bijective XCD swizzle: round-robin dispatch -> contiguous chunk per XCD
static __device__ __forceinline__ int xcd_swz(int bid, int nwg) {
    if (nwg < 16) return bid;
    int q = nwg >> 3, r = nwg & 7;
    int x = bid & 7, i = bid >> 3;
    return (x < r ? x * (q + 1) : r * (q + 1) + (x - r) * q) + i;
}

__global__ void rb_count_kernel(const int* __restrict__ rout, int P, int n_out,
                                int* __restrict__ cnt) {
    int k = threadIdx.x;
    if (k >= 27) return;
    const int* r = rout + (size_t)k * P;
    int lo = 0, hi = P;
    while (lo < hi) {
        int mid = (lo + hi) >> 1;
        if (r[mid] < n_out) lo = mid + 1; else hi = mid;
    }
    cnt[k] = lo;
}

// segs[k][b] = lower_bound(rout[k], b*gran), b in [0, nb]
__global__ void seg_build(const int* __restrict__ rout, const int* __restrict__ cnt,
                          int P, int nb, int gran, int* __restrict__ segs) {
    const int k = blockIdx.y;
    const int b = blockIdx.x * 256 + threadIdx.x;
    if (b > nb) return;
    const int target = b * gran;
    const int* r = rout + (size_t)k * P;
    int lo = 0, hi = cnt[k];
    while (lo < hi) {
        int m = (lo + hi) >> 1;
        if (r[m] < target) lo = m + 1; else hi = m;
    }
    segs[k * (nb + 1) + b] = lo;
}

__global__ void inv_build(const int* __restrict__ rin, const int* __restrict__ rout,
                          const int* __restrict__ cnt, int P, int n_out,
                          int* __restrict__ inv) {
    const int k = blockIdx.y;
    const int p = blockIdx.x * 256 + threadIdx.x;
    if (p < cnt[k])
        inv[(size_t)k * n_out + rout[(size_t)k * P + p]] = rin[(size_t)k * P + p];
}

// Pre-pack fp32 weights [T][CI][32] into MFMA B-frag bf16 order.
__global__ void prepack_w(const float* __restrict__ W, int T, int CI, int S,
                          short* __restrict__ pack) {
    int idx = blockIdx.x * 256 + threadIdx.x;     // over S*128
    if (idx >= S * 128) return;
    int l = idx & 63, h = (idx >> 6) & 1, s = idx >> 7;
    int co = (l & 15) + 16 * h;
#pragma unroll
    for (int j = 0; j < 8; j++) {
        int gk = s * 32 + (l >> 4) * 8 + j;
        int tap = gk / CI, cin = gk % CI;
        float w = (tap < T) ? W[((size_t)tap * CI + cin) * 32 + co] : 0.f;
        pack[(size_t)idx * 8 + j] = (short)f2bfu(w);
    }
}

// ---- MFMA gather conv, sorted rulebook, bf16 feat rows [n][32] ------------
template <bool OUT_BF16>
__global__ __launch_bounds__(256) void conv_mfma_sorted32(
        const unsigned short* __restrict__ feat, const short* __restrict__ Bp,
        const int* __restrict__ rin, const int* __restrict__ rout,
        const int* __restrict__ segs, int P, int nb16, int n_out,
        void* __restrict__ outv, float* __restrict__ stats) {
    __shared__ int invw[64];
    __shared__ float part[2][4][32];
    const int t = threadIdx.x, wv = t >> 6, lane = t & 63;
    const int row = lane & 15, grp = lane >> 4;
    const int bid = xcd_swz(blockIdx.x, gridDim.x);
    float ss0 = 0.f, qq0 = 0.f, ss1 = 0.f, qq1 = 0.f;

    for (int tile = 0; tile < 4; ++tile) {
        const int rowbase = bid * 256 + wv * 64 + tile * 16;
        if (rowbase >= n_out) break;
        const int tix = rowbase >> 4;
        int segv = 0;
        if (lane < 28)      segv = segs[lane * (nb16 + 1) + tix];
        else if (lane < 56) segv = segs[(lane - 28) * (nb16 + 1) + tix + 1];
        f32x4 d0 = {0.f, 0.f, 0.f, 0.f}, d1 = {0.f, 0.f, 0.f, 0.f};
        for (int k = 0; k < 27; ++k) {
            const int s0 = __shfl(segv, k);
            const int s1 = __shfl(segv, 28 + k);
            if (s0 == s1) continue;               // wave-uniform skip
            if (lane < 16) invw[wv * 16 + lane] = -1;
            const int e = s0 + lane;
            if (lane < 16 && e < s1)              // segment len <= 16
                invw[wv * 16 + (rout[(size_t)k * P + e] - rowbase)] = rin[(size_t)k * P + e];
            asm volatile("s_waitcnt lgkmcnt(0)" ::: "memory");
            const int rn = invw[wv * 16 + row];
            union { int u[4]; bf16x8 v; } ua;
            ua.u[0] = ua.u[1] = ua.u[2] = ua.u[3] = 0;
            if (rn >= 0)
                ua.v = *(const bf16x8*)(feat + (size_t)rn * 32 + grp * 8);
            const bf16x8 b0 = *(const bf16x8*)(Bp + ((size_t)(2 * k) * 64 + lane) * 8);
            const bf16x8 b1 = *(const bf16x8*)(Bp + ((size_t)(2 * k + 1) * 64 + lane) * 8);
            d0 = __builtin_amdgcn_mfma_f32_16x16x32_bf16(ua.v, b0, d0, 0, 0, 0);
            d1 = __builtin_amdgcn_mfma_f32_16x16x32_bf16(ua.v, b1, d1, 0, 0, 0);
        }
        const int m0 = rowbase + grp * 4;
#pragma unroll
        for (int i = 0; i < 4; i++) {
            if (m0 + i < n_out) {
                if (OUT_BF16) {
                    unsigned short* o = (unsigned short*)outv;
                    o[(size_t)(m0 + i) * 32 + row]      = (unsigned short)f2bfu(d0[i]);
                    o[(size_t)(m0 + i) * 32 + row + 16] = (unsigned short)f2bfu(d1[i]);
                } else {
                    float* o = (float*)outv;
                    o[(size_t)(m0 + i) * 32 + row]      = d0[i];
                    o[(size_t)(m0 + i) * 32 + row + 16] = d1[i];
                }
            }
            ss0 += d0[i]; qq0 += d0[i] * d0[i];
            ss1 += d1[i]; qq1 += d1[i] * d1[i];
        }
    }
#pragma unroll
    for (int d = 16; d <= 32; d <<= 1) {
        ss0 += __shfl_xor(ss0, d); qq0 += __shfl_xor(qq0, d);
        ss1 += __shfl_xor(ss1, d); qq1 += __shfl_xor(qq1, d);
    }
    if (lane < 16) {
        part[0][wv][row] = ss0; part[0][wv][row + 16] = ss1;
        part[1][wv][row] = qq0; part[1][wv][row + 16] = qq1;
    }
    __syncthreads();
    if (t < 64) {
        const int which = t >> 5, co = t & 31;
        atomicAdd(&stats[which * 32 + co],
                  part[which][0][co] + part[which][1][co] +
                  part[which][2][co] + part[which][3][co]);
    }
}

// ---- MFMA gather conv, dense inverse map, bf16 feat rows [n][16] ----------
__global__ __launch_bounds__(256) void conv_mfma_inv16(
        const unsigned short* __restrict__ feat, const short* __restrict__ Bp,
        const int* __restrict__ inv, int n_out,
        unsigned short* __restrict__ out, float* __restrict__ stats) {
    __shared__ float part[2][4][32];
    const int t = threadIdx.x, wv = t >> 6, lane = t & 63;
    const int row = lane & 15, grp = lane >> 4;
    const int bid = xcd_swz(blockIdx.x, gridDim.x);
    float ss0 = 0.f, qq0 = 0.f, ss1 = 0.f, qq1 = 0.f;

    for (int tile = 0; tile < 4; ++tile) {
        const int rowbase = bid * 256 + wv * 64 + tile * 16;
        if (rowbase >= n_out) break;
        const int j = rowbase + row;
        f32x4 d0 = {0.f, 0.f, 0.f, 0.f}, d1 = {0.f, 0.f, 0.f, 0.f};
        for (int s = 0; s < 14; ++s) {
            const int tap = 2 * s + (grp >> 1);
            const int cin0 = (grp & 1) * 8;
            int rn = -1;
            if (tap < 27 && j < n_out) rn = inv[(size_t)tap * n_out + j];
            union { int u[4]; bf16x8 v; } ua;
            ua.u[0] = ua.u[1] = ua.u[2] = ua.u[3] = 0;
            if (rn >= 0)
                ua.v = *(const bf16x8*)(feat + (size_t)rn * 16 + cin0);
            const bf16x8 b0 = *(const bf16x8*)(Bp + ((size_t)(2 * s) * 64 + lane) * 8);
            const bf16x8 b1 = *(const bf16x8*)(Bp + ((size_t)(2 * s + 1) * 64 + lane) * 8);
            d0 = __builtin_amdgcn_mfma_f32_16x16x32_bf16(ua.v, b0, d0, 0, 0, 0);
            d1 = __builtin_amdgcn_mfma_f32_16x16x32_bf16(ua.v, b1, d1, 0, 0, 0);
        }
        const int m0 = rowbase + grp * 4;
#pragma unroll
        for (int i = 0; i < 4; i++) {
            if (m0 + i < n_out) {
                out[(size_t)(m0 + i) * 32 + row]      = (unsigned short)f2bfu(d0[i]);
                out[(size_t)(m0 + i) * 32 + row + 16] = (unsigned short)f2bfu(d1[i]);
            }
            ss0 += d0[i]; qq0 += d0[i] * d0[i];
            ss1 += d1[i]; qq1 += d1[i] * d1[i];
        }
    }
#pragma unroll
    for (int d = 16; d <= 32; d <<= 1) {
        ss0 += __shfl_xor(ss0, d); qq0 += __shfl_xor(qq0, d);
        ss1 += __shfl_xor(ss1, d); qq1 += __shfl_xor(qq1, d);
    }
    if (lane < 16) {
        part[0][wv][row] = ss0; part[0][wv][row + 16] = ss1;
        part[1][wv][row] = qq0; part[1][wv][row + 16] = qq1;
    }
    __syncthreads();
    if (t < 64) {
        const int which = t >> 5, co = t & 31;
        atomicAdd(&stats[which * 32 + co],
                  part[which][0][co] + part[which][1][co] +
                  part[which][2][co] + part[which][3][co]);
    }
}

// ---- fp32 wave-tile gather conv, CIN=16 (rb1 chain + prune conv) ----------
template <int COUT, bool SIGMOID, bool STATS>
__global__ __launch_bounds__(256) void conv16_wave(
        const float* __restrict__ feat, const float* __restrict__ W,
        const int* __restrict__ rin, const int* __restrict__ rout,
        const int* __restrict__ segs, int P, int nb64, int n_out,
        float* __restrict__ out, float* __restrict__ stats) {
    __shared__ int invw[4 * 64];
    __shared__ float part[2][4][COUT];
    const int t = threadIdx.x, wv = t >> 6, lane = t & 63;
    const int bid = xcd_swz(blockIdx.x, gridDim.x);
    const int rowbase = bid * 256 + wv * 64;
    const bool active = rowbase < n_out;
    float acc[COUT];
#pragma unroll
    for (int co = 0; co < COUT; co++) acc[co] = 0.f;

    if (active) {
        const int tix = rowbase >> 6;
        int segv = 0;
        if (lane < 28)      segv = segs[lane * (nb64 + 1) + tix];
        else if (lane < 56) segv = segs[(lane - 28) * (nb64 + 1) + tix + 1];
        for (int k = 0; k < 27; ++k) {
            const int s0 = __shfl(segv, k);
            const int s1 = __shfl(segv, 28 + k);
            if (s0 == s1) continue;               // wave-uniform skip
            invw[wv * 64 + lane] = -1;
            const int e = s0 + lane;              // segment len <= 64
            if (e < s1)
                invw[wv * 64 + (rout[(size_t)k * P + e] - rowbase)] = rin[(size_t)k * P + e];
            asm volatile("s_waitcnt lgkmcnt(0)" ::: "memory");
            const int rn = invw[wv * 64 + lane];
            float f[16];
#pragma unroll
            for (int ci = 0; ci < 16; ci++) f[ci] = 0.f;
            if (rn >= 0) {
                const float* fr = feat + (size_t)rn * 16;
#pragma unroll
                for (int q = 0; q < 4; q++) {
                    const float4 v = *(const float4*)(fr + 4 * q);
                    f[4 * q] = v.x; f[4 * q + 1] = v.y;
                    f[4 * q + 2] = v.z; f[4 * q + 3] = v.w;
                }
            }
            const float* __restrict__ Wk = W + k * 16 * COUT;   // lane-uniform
#pragma unroll
            for (int ci = 0; ci < 16; ci++) {
                const float fv = f[ci];
#pragma unroll
                for (int co = 0; co < COUT; co++)
                    acc[co] = fmaf(fv, Wk[ci * COUT + co], acc[co]);
            }
        }
        const int j = rowbase + lane;
        if (j < n_out) {
#pragma unroll
            for (int co = 0; co < COUT; co++) {
                float v = acc[co];
                if (SIGMOID) v = 1.f / (1.f + expf(-v));
                out[(size_t)j * COUT + co] = v;
            }
        }
    }
    if (STATS) {
#pragma unroll
        for (int co = 0; co < COUT; co++) {
            float s = acc[co], s2 = s * s;
#pragma unroll
            for (int d = 1; d < 64; d <<= 1) {
                s += __shfl_xor(s, d);
                s2 += __shfl_xor(s2, d);
            }
            if (lane == 0) { part[0][wv][co] = s; part[1][wv][co] = s2; }
        }
        __syncthreads();
        if (t < 2 * COUT) {
            const int which = t / COUT, co = t - which * COUT;
            atomicAdd(&stats[which * COUT + co],
                      part[which][0][co] + part[which][1][co] +
                      part[which][2][co] + part[which][3][co]);
        }
    }
}

// ---- fp32 block gather conv (conv_input 5->16 only) -----------------------
template <int CIN, int COUT>
__global__ __launch_bounds__(256) void conv_gather(
        const float* __restrict__ feat, const float* __restrict__ W,
        const int* __restrict__ rin, const int* __restrict__ rout,
        const int* __restrict__ segs, int P, int n_out,
        float* __restrict__ out, float* __restrict__ stats) {
    __shared__ int2 invl[256];        // {tag k, rin}; valid iff tag == k
    __shared__ int seg[54];
    __shared__ float part[2][4][COUT];
    const int t = threadIdx.x;
    const int bid = xcd_swz(blockIdx.x, gridDim.x);
    const int j0 = bid * 256;
    const int nb1 = gridDim.x + 1;
    if (t < 54) seg[t] = segs[(t >> 1) * nb1 + bid + (t & 1)];
    invl[t] = make_int2(-1, -1);
    float acc[COUT];
#pragma unroll
    for (int co = 0; co < COUT; co++) acc[co] = 0.f;
    __syncthreads();

    for (int k = 0; k < 27; k++) {
        const int s0 = seg[2 * k], s1 = seg[2 * k + 1];
        if (s0 == s1) continue;
        const int idx = s0 + t;
        if (idx < s1)
            invl[rout[(size_t)k * P + idx] - j0] = make_int2(k, rin[(size_t)k * P + idx]);
        __syncthreads();
        const int2 e = invl[t];
        const int in = (e.x == k) ? e.y : -1;
        __syncthreads();

        float f[CIN];
#pragma unroll
        for (int ci = 0; ci < CIN; ci++) f[ci] = 0.f;
        if (in >= 0) {
            const float* fr = feat + (size_t)in * CIN;
#pragma unroll
            for (int ci = 0; ci < CIN; ci++) f[ci] = fr[ci];
        }
        const float* __restrict__ Wk = W + k * CIN * COUT;   // lane-uniform
#pragma unroll
        for (int ci = 0; ci < CIN; ci++) {
            const float fv = f[ci];
#pragma unroll
            for (int co = 0; co < COUT; co++)
                acc[co] = fmaf(fv, Wk[ci * COUT + co], acc[co]);
        }
    }

    const int j = j0 + t;
    if (j < n_out) {
#pragma unroll
        for (int co = 0; co < COUT; co++) out[(size_t)j * COUT + co] = acc[co];
    }
    const int wv = t >> 6, lane = t & 63;
#pragma unroll
    for (int co = 0; co < COUT; co++) {
        float s = acc[co], s2 = s * s;
#pragma unroll
        for (int d = 1; d < 64; d <<= 1) {
            s += __shfl_xor(s, d);
            s2 += __shfl_xor(s2, d);
        }
        if (lane == 0) { part[0][wv][co] = s; part[1][wv][co] = s2; }
    }
    __syncthreads();
    if (t < 2 * COUT) {
        const int which = t / COUT, co = t - which * COUT;
        atomicAdd(&stats[which * COUT + co],
                  part[which][0][co] + part[which][1][co] +
                  part[which][2][co] + part[which][3][co]);
    }
}

template <int C, bool RELU>
__global__ void bn_apply(const float* __restrict__ x, const float* __restrict__ stats,
                         const float* __restrict__ gg, const float* __restrict__ bb,
                         int n, float* __restrict__ y) {
    const float nf = (float)n;
    const long long total = (long long)n * C;
    for (long long idx = (long long)blockIdx.x * blockDim.x + threadIdx.x;
         idx < total; idx += (long long)gridDim.x * blockDim.x) {
        int ch = (int)(idx & (C - 1));
        float m = stats[ch] / nf;
        float v = stats[C + ch] / nf - m * m;
        float r = rsqrtf(v + 1e-3f);
        float val = gg[ch] * (x[idx] - m) * r + bb[ch];
        if (RELU) val = fmaxf(val, 0.f);
        y[idx] = val;
    }
}

template <int C>
__global__ void bn_apply_addrelu(const float* __restrict__ x,
                                 const float* __restrict__ skip,
                                 const float* __restrict__ stats,
                                 const float* __restrict__ gg,
                                 const float* __restrict__ bb,
                                 int n, float* __restrict__ y) {
    const float nf = (float)n;
    const long long total = (long long)n * C;
    for (long long idx = (long long)blockIdx.x * blockDim.x + threadIdx.x;
         idx < total; idx += (long long)gridDim.x * blockDim.x) {
        int ch = (int)(idx & (C - 1));
        float m = stats[ch] / nf;
        float v = stats[C + ch] / nf - m * m;
        float r = rsqrtf(v + 1e-3f);
        float val = gg[ch] * (x[idx] - m) * r + bb[ch] + skip[idx];
        y[idx] = fmaxf(val, 0.f);
    }
}

// BN over bf16 in -> bf16 out (stage-2 feature buffers)
template <int C>
__global__ void bn_apply_b(const unsigned short* __restrict__ x,
                           const float* __restrict__ stats,
                           const float* __restrict__ gg, const float* __restrict__ bb,
                           int n, unsigned short* __restrict__ y) {
    const float nf = (float)n;
    const long long total = (long long)n * C;
    for (long long idx = (long long)blockIdx.x * blockDim.x + threadIdx.x;
         idx < total; idx += (long long)gridDim.x * blockDim.x) {
        int ch = (int)(idx & (C - 1));
        float m = stats[ch] / nf;
        float v = stats[C + ch] / nf - m * m;
        float r = rsqrtf(v + 1e-3f);
        float val = gg[ch] * (bf2f(x[idx]) - m) * r + bb[ch];
        val = fmaxf(val, 0.f);
        y[idx] = (unsigned short)f2bfu(val);
    }
}

// BN(x fp32) + bf16 skip + ReLU -> bf16 (next block input) or fp32 (final out)
template <int C, bool OUT_BF16>
__global__ void bn_addrelu_sb(const float* __restrict__ x,
                              const unsigned short* __restrict__ skip,
                              const float* __restrict__ stats,
                              const float* __restrict__ gg,
                              const float* __restrict__ bb,
                              int n, void* __restrict__ yv) {
    const float nf = (float)n;
    const long long total = (long long)n * C;
    for (long long idx = (long long)blockIdx.x * blockDim.x + threadIdx.x;
         idx < total; idx += (long long)gridDim.x * blockDim.x) {
        int ch = (int)(idx & (C - 1));
        float m = stats[ch] / nf;
        float v = stats[C + ch] / nf - m * m;
        float r = rsqrtf(v + 1e-3f);
        float val = gg[ch] * (x[idx] - m) * r + bb[ch] + bf2f(skip[idx]);
        val = fmaxf(val, 0.f);
        if (OUT_BF16) ((unsigned short*)yv)[idx] = (unsigned short)f2bfu(val);
        else          ((float*)yv)[idx] = val;
    }
}

// ---- exact top-k: 4-pass byte radix, LDS-privatized histograms ------------
__global__ __launch_bounds__(256) void hist_pass(const float* __restrict__ imp, int n,
                                                 int pass, const int* __restrict__ state,
                                                 int* __restrict__ hist) {
    __shared__ int lh[256];
    const int t = threadIdx.x;
    lh[t] = 0;
    __syncthreads();
    const int shift = 24 - 8 * pass;
    unsigned prefix = 0;
    if (pass > 0) prefix = (unsigned)state[0];
    for (int i = blockIdx.x * 256 + t; i < n; i += gridDim.x * 256) {
        unsigned u = __float_as_uint(imp[i]);
        if (pass == 0 || (u >> (shift + 8)) == prefix)
            atomicAdd(&lh[(u >> shift) & 0xFFu], 1);
    }
    __syncthreads();
    if (lh[t]) atomicAdd(&hist[pass * 256 + t], lh[t]);
}

__global__ __launch_bounds__(256) void scan_byte(const int* __restrict__ hist,
                                                 int kkeep, int pass,
                                                 int* __restrict__ state) {
    __shared__ int h[256];
    const int t = threadIdx.x;
    h[t] = hist[pass * 256 + t];
    __syncthreads();
    if (t == 0) {
        const int target = (pass == 0) ? kkeep : state[1];
        int acc = 0; int b = 255;
        for (; b > 0; b--) {
            if (acc + h[b] >= target) break;
            acc += h[b];
        }
        unsigned prefix = (pass == 0) ? 0u : (unsigned)state[0];
        prefix = (prefix << 8) | (unsigned)b;
        state[0] = (int)prefix;
        state[1] = target - acc;
        if (pass == 3) state[2] = (int)prefix;   // exact bits of kth largest
    }
}

// prune + emit bf16 pruned features (Ab) in one pass; fp32 A dies here
__global__ void prune_mask_ab(const float* __restrict__ x, const float* __restrict__ imp,
                              const int* __restrict__ state, int n,
                              unsigned short* __restrict__ ab) {
    const unsigned K = (unsigned)state[2];
    int i = blockIdx.x * blockDim.x + threadIdx.x;
    if (i >= n) return;
    float im = imp[i];
    float mult = (__float_as_uint(im) >= K) ? im : 0.f;
#pragma unroll
    for (int c = 0; c < 16; c++)
        ab[(size_t)i * 16 + c] = (unsigned short)f2bfu(x[(size_t)i * 16 + c] * mult);
}

extern "C" void kernel_launch(void* const* d_in, const int* in_sizes, int n_in,
                              void* d_out, int out_size, void* d_ws, size_t ws_size,
                              hipStream_t stream) {
    const float* vf    = (const float*)d_in[0];
    const float* W_in  = (const float*)d_in[1];
    const float* g_in  = (const float*)d_in[2];
    const float* b_in  = (const float*)d_in[3];
    const float* Wb1   = (const float*)d_in[4];
    const float* gb1   = (const float*)d_in[6];
    const float* beb1  = (const float*)d_in[7];
    const float* Wp    = (const float*)d_in[8];
    const float* Wd    = (const float*)d_in[9];
    const float* g_d   = (const float*)d_in[10];
    const float* b_d   = (const float*)d_in[11];
    const float* Wb2   = (const float*)d_in[12];
    const float* gb2   = (const float*)d_in[14];
    const float* beb2  = (const float*)d_in[15];
    const int* rb1_in  = (const int*)d_in[16];
    const int* rb1_out = (const int*)d_in[17];
    const int* rbd_in  = (const int*)d_in[18];
    const int* rbd_out = (const int*)d_in[19];
    const int* rb2_in  = (const int*)d_in[20];
    const int* rb2_out = (const int*)d_in[21];

    const int N  = in_sizes[0] / 5;
    const int P1 = in_sizes[16] / 27;
    const int Pd = in_sizes[18] / 27;
    const int P2 = in_sizes[20] / 27;
    const int n2 = out_size / 32;
    const int kkeep = N - N / 2;

    const int gs1   = (N + 255) / 256;        // 256-row blocks over N
    const int gm2   = (n2 + 255) / 256;       // 256-row MFMA blocks over n2
    const int nb16  = (n2 + 15) / 16;         // 16-row tiles over n2
    const int nb64  = (N + 63) / 64;          // 64-row tiles over N
    const int gew   = 2048;

    // workspace layout (4-byte words); regions 16B-aligned
    auto pad4 = [](size_t v) { return (v + 3) & ~(size_t)3; };
    float* A     = (float*)d_ws;                       // N x 16 fp32 (stage 1)
    float* B     = A   + pad4((size_t)N * 16);         // N x 16 fp32 (Ab/segs16 later)
    float* imp   = B   + pad4((size_t)N * 16);         // N (packs later)
    float* FI    = imp + pad4((size_t)N);              // 32n2: invd first, F fp32 later
    float* Dbf   = FI  + pad4((size_t)n2 * 32);        // 16n2 words: Db bf16 [n2][32]
    float* Ebf   = Dbf + pad4((size_t)n2 * 16);        // 16n2 words: Eb bf16 [n2][32]
    float* stats = Ebf + pad4((size_t)n2 * 16);        // 64
    int*   cnt1  = (int*)(stats + 64);
    int*   cntd  = cnt1 + 32;
    int*   cnt2  = cntd + 32;
    int*   hist4 = cnt2 + 32;                          // 4 * 256
    int*   state = hist4 + 1024;                       // 8
    int*   segs1 = state + 8;                          // 27 * (gs1+1)
    int*   segs64 = segs1 + 27 * (gs1 + 1);            // 27 * (nb64+1)
    int*   invd   = (int*)FI;                          // 27*n2 ints (dead before F)
    float* F      = FI;                                // n2 x 32 fp32 (conv2 out)
    unsigned short* Ab = (unsigned short*)B;           // N x 16 bf16 (B dead)
    int*   segs16 = (int*)(B + pad4((size_t)N * 8));   // 27*(nb16+1) (B tail)
    short* pack2  = (short*)imp;                       // 4 * 27648 shorts (imp dead)
    short* packd  = pack2 + 4 * 27648;                 // 14336 shorts
    unsigned short* Db = (unsigned short*)Dbf;
    unsigned short* Eb = (unsigned short*)Ebf;
    float* OUT   = (float*)d_out;
    float* C2    = OUT;                                // stage-1 scratch (16N <= 32n2)

    rb_count_kernel<<<1, 32, 0, stream>>>(rb1_out, P1, N,  cnt1);
    rb_count_kernel<<<1, 32, 0, stream>>>(rbd_out, Pd, n2, cntd);
    rb_count_kernel<<<1, 32, 0, stream>>>(rb2_out, P2, n2, cnt2);
    seg_build<<<dim3((gs1 + 256) / 256, 27), 256, 0, stream>>>(rb1_out, cnt1, P1, gs1, 256, segs1);
    seg_build<<<dim3((nb64 + 256) / 256, 27), 256, 0, stream>>>(rb1_out, cnt1, P1, nb64, 64, segs64);

    // ---- stage 1 (fp32): conv_input + BN + ReLU -> A
    hipMemsetAsync(stats, 0, 64 * 4, stream);
    conv_gather<5, 16><<<gs1, 256, 0, stream>>>(vf, W_in, rb1_in, rb1_out, segs1, P1, N, B, stats);
    bn_apply<16, true><<<gew, 256, 0, stream>>>(B, stats, g_in, b_in, N, A);

    for (int i = 0; i < 2; i++) {
        const float* W0 = Wb1 + (size_t)(i * 2 + 0) * 27 * 256;
        const float* W1 = Wb1 + (size_t)(i * 2 + 1) * 27 * 256;
        hipMemsetAsync(stats, 0, 64 * 4, stream);
        conv16_wave<16, false, true><<<gs1, 256, 0, stream>>>(A, W0, rb1_in, rb1_out, segs64, P1, nb64, N, B, stats);
        bn_apply<16, true><<<gew, 256, 0, stream>>>(B, stats, gb1 + (i * 2 + 0) * 16, beb1 + (i * 2 + 0) * 16, N, B);
        hipMemsetAsync(stats, 0, 64 * 4, stream);
        conv16_wave<16, false, true><<<gs1, 256, 0, stream>>>(B, W1, rb1_in, rb1_out, segs64, P1, nb64, N, C2, stats);
        bn_apply_addrelu<16><<<gew, 256, 0, stream>>>(C2, A, stats, gb1 + (i * 2 + 1) * 16, beb1 + (i * 2 + 1) * 16, N, A);
    }

    // ---- pruning: imp = sigmoid(conv 16->1); exact top-k via byte radix
    conv16_wave<1, true, false><<<gs1, 256, 0, stream>>>(A, Wp, rb1_in, rb1_out, segs64, P1, nb64, N, imp, stats);
    hipMemsetAsync(hist4, 0, 1024 * 4, stream);
    for (int p = 0; p < 4; p++) {
        hist_pass<<<128, 256, 0, stream>>>(imp, N, p, state, hist4);
        scan_byte<<<1, 256, 0, stream>>>(hist4, kkeep, p, state);
    }
    prune_mask_ab<<<(N + 255) / 256, 256, 0, stream>>>(A, imp, state, N, Ab);

    // ---- stage-2 setup (B tail and imp regions are dead now)
    seg_build<<<dim3((nb16 + 256) / 256, 27), 256, 0, stream>>>(rb2_out, cnt2, P2, nb16, 16, segs16);
    for (int w = 0; w < 4; w++)
        prepack_w<<<14, 256, 0, stream>>>(Wb2 + (size_t)w * 27 * 1024, 27, 32, 27, pack2 + (size_t)w * 27648);
    prepack_w<<<7, 256, 0, stream>>>(Wd, 27, 16, 14, packd);
    hipMemsetAsync(invd, 0xFF, (size_t)27 * n2 * 4, stream);
    inv_build<<<dim3((Pd + 255) / 256, 27), 256, 0, stream>>>(rbd_in, rbd_out, cntd, Pd, n2, invd);

    // ---- strided downsample 16->32 (MFMA, bf16 in/out) + BN -> Db
    hipMemsetAsync(stats, 0, 64 * 4, stream);
    conv_mfma_inv16<<<gm2, 256, 0, stream>>>(Ab, packd, invd, n2, Db, stats);
    bn_apply_b<32><<<gew, 256, 0, stream>>>(Db, stats, g_d, b_d, n2, Db);

    // ---- conv2: 2x SparseBasicBlock @32 (MFMA, bf16 features)
    for (int i = 0; i < 2; i++) {
        const short* P0 = pack2 + (size_t)(i * 2 + 0) * 27648;
        const short* P1w = pack2 + (size_t)(i * 2 + 1) * 27648;
        hipMemsetAsync(stats, 0, 64 * 4, stream);
        conv_mfma_sorted32<true><<<gm2, 256, 0, stream>>>(Db, P0, rb2_in, rb2_out, segs16, P2, nb16, n2, Eb, stats);
        bn_apply_b<32><<<gew, 256, 0, stream>>>(Eb, stats, gb2 + (i * 2 + 0) * 32, beb2 + (i * 2 + 0) * 32, n2, Eb);
        hipMemsetAsync(stats, 0, 64 * 4, stream);
        conv_mfma_sorted32<false><<<gm2, 256, 0, stream>>>(Eb, P1w, rb2_in, rb2_out, segs16, P2, nb16, n2, F, stats);
        if (i == 0)
            bn_addrelu_sb<32, true><<<gew, 256, 0, stream>>>(F, Db, stats, gb2 + 32, beb2 + 32, n2, Db);
        else
            bn_addrelu_sb<32, false><<<gew, 256, 0, stream>>>(F, Db, stats, gb2 + 96, beb2 + 96, n2, OUT);
    }
}